// Round 8
// baseline (2678.178 us; speedup 1.0000x reference)
//
#include <hip/hip_runtime.h>
#include <stdint.h>

#define BATCH 2048
#define NDIM  1024
#define HID   1024
#define TSTEPS 32

// out layout (FP32 elems): final[2048*1024] | delta[32*2048] | total[2048] | vinit[2048*1024]
#define OUT_FINAL 0
#define OUT_DELTA 2097152
#define OUT_TOTAL 2162688
#define OUT_VINIT 2164736

// scratch inside the delta region (byte offsets from out+OUT_DELTA; 262144 B avail)
#define SC_ROWSUM 0        // 2048 f32
#define SC_TGT    8192     // 2048 f32
#define SC_TOTAL  16384    // 2048 f32
#define SC_BIAS   24576    // 3072 f32 (b1|b2|b3)
#define SC_FLAG   36864    // u32  (1 = inputs bf16, 0 = inputs fp32)

__device__ __forceinline__ float bf2f(ushort u) {
  union { uint32_t u; float f; } v; v.u = ((uint32_t)u) << 16; return v.f;
}
__device__ __forceinline__ ushort f2bf(float f) {
  union { float f; uint32_t u; } v; v.f = f;
  uint32_t u = v.u;
  u += 0x7fffu + ((u >> 16) & 1u);   // RNE
  return (ushort)(u >> 16);
}

typedef __attribute__((ext_vector_type(8))) short bf16x8;
typedef __attribute__((ext_vector_type(8))) unsigned short u16x8;
typedef __attribute__((ext_vector_type(4))) float f32x4;

// ---- dtype flag: bf16 iff any even-index ushort of first 64K ushorts != 0 ---
__global__ __launch_bounds__(256) void flag_k(const void* __restrict__ init,
                                              uint32_t* __restrict__ flag) {
  const ushort* p = (const ushort*)init;
  __shared__ uint32_t acc[256];
  uint32_t a = 0;
  for (int i = threadIdx.x; i < 32768; i += 256) a |= p[2 * i];
  acc[threadIdx.x] = a;
  __syncthreads();
  for (int s = 128; s > 0; s >>= 1) {
    if (threadIdx.x < s) acc[threadIdx.x] |= acc[threadIdx.x + s];
    __syncthreads();
  }
  if (threadIdx.x == 0) *flag = (acc[0] != 0) ? 1u : 0u;
}

// ---- zero rowsum|tgt|total (6144 contiguous f32) ----------------------------
__global__ __launch_bounds__(256) void zero_k(float* __restrict__ p) {
  p[blockIdx.x * 256 + threadIdx.x] = 0.f;   // grid 24
}

// ---- canonicalize biases -> fp32 scratch ------------------------------------
__global__ __launch_bounds__(256) void canon_b_k(const void* b1, const void* b2,
                                                 const void* b3,
                                                 float* __restrict__ dst,
                                                 const uint32_t* __restrict__ flag) {
  const void* src = (blockIdx.x == 0) ? b1 : (blockIdx.x == 1) ? b2 : b3;
  float* d = dst + blockIdx.x * 1024;
  const bool isbf = (*flag != 0);
  for (int i = threadIdx.x; i < 1024; i += 256)
    d[i] = isbf ? bf2f(((const ushort*)src)[i]) : ((const float*)src)[i];
}

// ---- 64x64 MFMA GEMM, B staged TRANSPOSED from raw W[k][n] ------------------
// ASRC 0: raw init via flag.  1: a1 bf16 + relu.  2: h2 bf16 plain.
// EPI  0: plain bf16 store.   1: relu bf16 store. 2: softmax partials.
template <int ASRC, int EPI>
__global__ __launch_bounds__(256) void gemm_t(const void* __restrict__ A,
                                              const void* __restrict__ W,
                                              const float* __restrict__ bias,
                                              ushort* __restrict__ Cout,
                                              const int* __restrict__ tpos,
                                              float* __restrict__ rowsum,
                                              float* __restrict__ tgt,
                                              const uint32_t* __restrict__ flag,
                                              int tstep) {
  constexpr int BM = 64, BN = 64, BK = 32, BKP = 40, K = 1024;
  __shared__ ushort Asm[BM * BKP];   // 5 KB (stride 40 ushorts = 80 B)
  __shared__ ushort Bsm[BN * BKP];   // 5 KB
  const int tid = threadIdx.x;
  const int w = tid >> 6, lane = tid & 63;
  const int q = lane >> 4, r = lane & 15;
  const int n0 = blockIdx.x * BN;    // 16 n-blocks
  const int m0 = blockIdx.y * BM;    // 32 m-blocks
  const bool isbf = (*flag != 0);

  const int srow = tid >> 2, scol = (tid & 3) * 8;   // A staging: 8 elems/thread
  const int kk = tid >> 3, ng = (tid & 7) * 8;       // B staging: 8 n's/thread

  f32x4 acc[4];
  #pragma unroll
  for (int nt = 0; nt < 4; ++nt)
    #pragma unroll
    for (int e = 0; e < 4; ++e) acc[nt][e] = 0.f;

  for (int k0 = 0; k0 < K; k0 += BK) {
    // ---- A tile: rows m0+srow, cols k0+scol..+8 ----
    u16x8 av;
    if constexpr (ASRC == 0) {
      if (isbf) {
        av = *(const u16x8*)((const ushort*)A + (size_t)(m0 + srow) * K + k0 + scol);
      } else {
        const float* fp = (const float*)A + (size_t)(m0 + srow) * K + k0 + scol;
        const float4 fa = *(const float4*)fp;
        const float4 fb = *(const float4*)(fp + 4);
        av[0] = f2bf(fa.x); av[1] = f2bf(fa.y); av[2] = f2bf(fa.z); av[3] = f2bf(fa.w);
        av[4] = f2bf(fb.x); av[5] = f2bf(fb.y); av[6] = f2bf(fb.z); av[7] = f2bf(fb.w);
      }
    } else {
      av = *(const u16x8*)((const ushort*)A + (size_t)(m0 + srow) * K + k0 + scol);
      if constexpr (ASRC == 1) {
        #pragma unroll
        for (int e = 0; e < 8; ++e) av[e] = (av[e] & 0x8000u) ? (unsigned short)0 : av[e];
      }
    }
    // ---- B tile transposed: Bsm[n][kk] = W[k0+kk][n0+n], 8 n's per thread ----
    ushort bw[8];
    if (isbf) {
      const u16x8 wv = *(const u16x8*)((const ushort*)W + (size_t)(k0 + kk) * NDIM + n0 + ng);
      #pragma unroll
      for (int j = 0; j < 8; ++j) bw[j] = wv[j];
    } else {
      const float* fp = (const float*)W + (size_t)(k0 + kk) * NDIM + n0 + ng;
      const float4 fa = *(const float4*)fp;
      const float4 fb = *(const float4*)(fp + 4);
      bw[0] = f2bf(fa.x); bw[1] = f2bf(fa.y); bw[2] = f2bf(fa.z); bw[3] = f2bf(fa.w);
      bw[4] = f2bf(fb.x); bw[5] = f2bf(fb.y); bw[6] = f2bf(fb.z); bw[7] = f2bf(fb.w);
    }
    __syncthreads();                       // prior-iteration LDS reads done
    *(u16x8*)(Asm + srow * BKP + scol) = av;
    #pragma unroll
    for (int j = 0; j < 8; ++j) Bsm[(ng + j) * BKP + kk] = bw[j];
    __syncthreads();                       // tiles visible
    const bf16x8 af = *(const bf16x8*)(Asm + (w * 16 + r) * BKP + q * 8);
    #pragma unroll
    for (int nt = 0; nt < 4; ++nt) {
      const bf16x8 bfr = *(const bf16x8*)(Bsm + (nt * 16 + r) * BKP + q * 8);
      acc[nt] = __builtin_amdgcn_mfma_f32_16x16x32_bf16(af, bfr, acc[nt], 0, 0, 0);
    }
  }

  if constexpr (EPI == 2) {
    #pragma unroll
    for (int reg = 0; reg < 4; ++reg) {
      const int grow = m0 + w * 16 + q * 4 + reg;           // 0..2047
      const int tp = tpos[tstep * BATCH + grow];
      float s = 0.f;
      #pragma unroll
      for (int nt = 0; nt < 4; ++nt) {
        const int gcol = n0 + nt * 16 + r;
        const float v = acc[nt][reg] + bias[gcol];
        if (gcol == tp) tgt[grow] = v;
        s += __expf(v);
      }
      s += __shfl_xor(s, 1);
      s += __shfl_xor(s, 2);
      s += __shfl_xor(s, 4);
      s += __shfl_xor(s, 8);
      if (r == 0) atomicAdd(&rowsum[grow], s);
    }
  } else {
    #pragma unroll
    for (int nt = 0; nt < 4; ++nt) {
      #pragma unroll
      for (int reg = 0; reg < 4; ++reg) {
        const int grow = m0 + w * 16 + q * 4 + reg;
        const int gcol = n0 + nt * 16 + r;
        float v = acc[nt][reg] + bias[gcol];
        if constexpr (EPI == 1) v = (v > 0.f) ? v : 0.f;
        Cout[(size_t)grow * NDIM + gcol] = f2bf(v);
      }
    }
  }
}

// ---- per-step: total += tgt - log(rowsum); a1 += sign*W1[tp]; reset ---------
// bit-before-step-t = init_bit XOR parity(#matches t'<t)
__global__ __launch_bounds__(256) void step_k(ushort* __restrict__ a1,
                                              const void* __restrict__ init,
                                              const void* __restrict__ W1,
                                              const int* __restrict__ tpos,
                                              float* __restrict__ rowsum,
                                              const float* __restrict__ tgt,
                                              float* __restrict__ total,
                                              const uint32_t* __restrict__ flag,
                                              int t) {
  const int m = blockIdx.x;
  const int k = threadIdx.x * 4;
  const bool isbf = (*flag != 0);
  const int tp = tpos[t * BATCH + m];
  const float b0 = isbf ? bf2f(((const ushort*)init)[(size_t)m * NDIM + tp])
                        : ((const float*)init)[(size_t)m * NDIM + tp];
  int cnt = 0;
  for (int u = 0; u < t; ++u) cnt += (tpos[u * BATCH + m] == tp) ? 1 : 0;
  const float bit = (cnt & 1) ? (1.f - b0) : b0;
  const float s = 1.f - 2.f * bit;

  float wx, wy, wz, ww;
  if (isbf) {
    const ushort4 wv = *(const ushort4*)((const ushort*)W1 + (size_t)tp * HID + k);
    wx = bf2f(wv.x); wy = bf2f(wv.y); wz = bf2f(wv.z); ww = bf2f(wv.w);
  } else {
    const float4 wv = *(const float4*)((const float*)W1 + (size_t)tp * HID + k);
    wx = wv.x; wy = wv.y; wz = wv.z; ww = wv.w;
  }
  ushort4 a = *(const ushort4*)(a1 + (size_t)m * HID + k);
  a.x = f2bf(bf2f(a.x) + s * wx);
  a.y = f2bf(bf2f(a.y) + s * wy);
  a.z = f2bf(bf2f(a.z) + s * wz);
  a.w = f2bf(bf2f(a.w) + s * ww);
  *(ushort4*)(a1 + (size_t)m * HID + k) = a;
  if (threadIdx.x == 0) {
    total[m] += tgt[m] - logf(rowsum[m]);
    rowsum[m] = 0.f;
  }
}

// ---- total_log (fp32) -> d_out (before delta scratch is clobbered) ----------
__global__ __launch_bounds__(256) void finalize_k(const float* __restrict__ total,
                                                  float* __restrict__ out_total) {
  const int m = blockIdx.x * 256 + threadIdx.x;
  out_total[m] = total[m];
}

// ---- final samples (fp32): init bits + per-position flip checks -------------
__global__ __launch_bounds__(256) void out_final_k(const void* __restrict__ init,
                                                   const int* __restrict__ tpos,
                                                   float* __restrict__ out,
                                                   const uint32_t* __restrict__ flag) {
  const int m = blockIdx.x;
  const int k = threadIdx.x * 4;      // this thread owns cols k..k+3
  const bool isbf = (*flag != 0);
  float v[4];
  if (isbf) {
    const ushort4 iv = *(const ushort4*)((const ushort*)init + (size_t)m * NDIM + k);
    v[0] = bf2f(iv.x); v[1] = bf2f(iv.y); v[2] = bf2f(iv.z); v[3] = bf2f(iv.w);
  } else {
    const float4 iv = *(const float4*)((const float*)init + (size_t)m * NDIM + k);
    v[0] = iv.x; v[1] = iv.y; v[2] = iv.z; v[3] = iv.w;
  }
  for (int t = 0; t < TSTEPS; ++t) {
    const int tp = tpos[t * BATCH + m];
    if ((tp >> 2) == (int)threadIdx.x) {
      const int j = tp & 3;
      v[j] = 1.f - v[j];
    }
  }
  float4 o; o.x = v[0]; o.y = v[1]; o.z = v[2]; o.w = v[3];
  *(float4*)(out + OUT_FINAL + (size_t)m * NDIM + k) = o;
}

// ---- very_init_samples (fp32) -----------------------------------------------
__global__ __launch_bounds__(256) void out_vinit_k(const void* __restrict__ init,
                                                   float* __restrict__ out,
                                                   const uint32_t* __restrict__ flag) {
  const int i = (blockIdx.x * 256 + threadIdx.x) * 4;   // grid 2048 -> 2M elems
  float4 o;
  if (*flag) {
    const ushort4 iv = *(const ushort4*)((const ushort*)init + i);
    o.x = bf2f(iv.x); o.y = bf2f(iv.y); o.z = bf2f(iv.z); o.w = bf2f(iv.w);
  } else {
    o = *(const float4*)((const float*)init + i);
  }
  *(float4*)(out + OUT_VINIT + i) = o;
}

// ---- delta = float(tpos) — LAST (clobbers delta-region scratch) -------------
__global__ __launch_bounds__(256) void out_delta_k(const int* __restrict__ tpos,
                                                   float* __restrict__ out) {
  const int i = blockIdx.x * 256 + threadIdx.x;   // grid 256 -> 65536
  out[OUT_DELTA + i] = (float)tpos[i];
}

extern "C" void kernel_launch(void* const* d_in, const int* in_sizes, int n_in,
                              void* d_out, int out_size, void* d_ws, size_t ws_size,
                              hipStream_t stream) {
  const void* init = d_in[0];
  const int* tpos  = (const int*)d_in[1];
  const void* W1 = d_in[2];
  const void* b1 = d_in[3];
  const void* W2 = d_in[4];
  const void* b2 = d_in[5];
  const void* W3 = d_in[6];
  const void* b3 = d_in[7];
  float* out = (float*)d_out;   // FP32 output buffer (17 MB)

  // d_out-resident scratch ONLY (d_ws and d_in never written)
  ushort*   a1     = (ushort*)(out + OUT_FINAL);   // 4 MB bf16 carry (in 8 MB region)
  ushort*   h2     = (ushort*)(out + OUT_VINIT);   // 4 MB per-step hidden (in 8 MB region)
  char*     sc     = (char*)(out + OUT_DELTA);     // 256 KB small scratch
  float*    rowsum = (float*)(sc + SC_ROWSUM);
  float*    tgt    = (float*)(sc + SC_TGT);
  float*    total  = (float*)(sc + SC_TOTAL);
  float*    biases = (float*)(sc + SC_BIAS);
  uint32_t* flag   = (uint32_t*)(sc + SC_FLAG);

  flag_k<<<1, 256, 0, stream>>>(init, flag);
  zero_k<<<24, 256, 0, stream>>>(rowsum);          // rowsum|tgt|total contiguous
  canon_b_k<<<3, 256, 0, stream>>>(b1, b2, b3, biases, flag);

  // a1 = init @ W1 + b1
  gemm_t<0, 0><<<dim3(16, 32), 256, 0, stream>>>(init, W1, biases + 0, a1,
                                                 nullptr, nullptr, nullptr, flag, 0);

  for (int t = 0; t < TSTEPS; ++t) {
    // h2 = relu(relu(a1) @ W2 + b2)
    gemm_t<1, 1><<<dim3(16, 32), 256, 0, stream>>>(a1, W2, biases + 1024, h2,
                                                   nullptr, nullptr, nullptr, flag, 0);
    // logits = h2 @ W3 + b3 -> exp-sum + target logit
    gemm_t<2, 2><<<dim3(16, 32), 256, 0, stream>>>(h2, W3, biases + 2048, nullptr,
                                                   tpos, rowsum, tgt, flag, t);
    // total/carry update (flip sign recomputed arithmetically)
    step_k<<<BATCH, 256, 0, stream>>>(a1, init, W1, tpos, rowsum, tgt, total, flag, t);
  }

  finalize_k<<<8, 256, 0, stream>>>(total, out + OUT_TOTAL);        // reads scratch
  out_final_k<<<BATCH, 256, 0, stream>>>(init, tpos, out, flag);    // overwrites a1
  out_vinit_k<<<2048, 256, 0, stream>>>(init, out, flag);           // overwrites h2
  out_delta_k<<<256, 256, 0, stream>>>(tpos, out);                  // clobbers scratch, LAST
}

// Round 9
// 651.858 us; speedup vs baseline: 4.1085x; 4.1085x over previous
//
#include <hip/hip_runtime.h>
#include <stdint.h>

#define BATCH 2048
#define NDIM  1024
#define HID   1024
#define TSTEPS 32

// out layout (FP32 elems): final[2048*1024] | delta[32*2048] | total[2048] | vinit[2048*1024]
#define OUT_FINAL 0
#define OUT_DELTA 2097152
#define OUT_TOTAL 2162688
#define OUT_VINIT 2164736

// ---- fallback-path scratch inside the delta region (bytes from out+OUT_DELTA)
#define SC_ROWSUM 0        // 2048 f32
#define SC_TGT    8192     // 2048 f32
#define SC_TOTAL  16384    // 2048 f32
#define SC_BIAS   24576    // 3072 f32
#define SC_FLAG   36864    // u32

// ---- fast-path d_ws layout (bytes) ----
#define WF_WT1    0u           // 2 MB  W1^T bf16 [n][k]
#define WF_WT2    2097152u     // 2 MB
#define WF_WT3    4194304u     // 2 MB
#define WF_A1     6291456u     // 8 MB  fp32 a1 carry [2048][1024]
#define WF_BIAS   14680064u    // 12 KB fp32 b1|b2|b3
#define WF_SIGNS  14692352u    // 64 KB u8 bit-before-flip per (t,m)
#define WF_ROWSUM 14757888u    // 256 KB fp32[65536]
#define WF_TGT    15020032u    // 256 KB fp32[65536]
#define WF_FLAG   15282176u    // 4 B
#define WF_H1     15286272u    // CH*4 MB bf16
// h2 follows h1: CH*4 MB

__device__ __forceinline__ float bf2f(ushort u) {
  union { uint32_t u; float f; } v; v.u = ((uint32_t)u) << 16; return v.f;
}
__device__ __forceinline__ ushort f2bf(float f) {
  union { float f; uint32_t u; } v; v.f = f;
  uint32_t u = v.u;
  u += 0x7fffu + ((u >> 16) & 1u);   // RNE
  return (ushort)(u >> 16);
}

typedef __attribute__((ext_vector_type(8))) short bf16x8;
typedef __attribute__((ext_vector_type(8))) unsigned short u16x8;
typedef __attribute__((ext_vector_type(4))) float f32x4;

__device__ __forceinline__ void gload_lds16(const void* g, void* l) {
  __builtin_amdgcn_global_load_lds((const __attribute__((address_space(1))) void*)g,
                                   (__attribute__((address_space(3))) void*)l, 16, 0, 0);
}

// ---- dtype flag: bf16 iff any even-index ushort of first 64K ushorts != 0 ---
__global__ __launch_bounds__(256) void flag_k(const void* __restrict__ init,
                                              uint32_t* __restrict__ flag) {
  const ushort* p = (const ushort*)init;
  __shared__ uint32_t acc[256];
  uint32_t a = 0;
  for (int i = threadIdx.x; i < 32768; i += 256) a |= p[2 * i];
  acc[threadIdx.x] = a;
  __syncthreads();
  for (int s = 128; s > 0; s >>= 1) {
    if (threadIdx.x < s) acc[threadIdx.x] |= acc[threadIdx.x + s];
    __syncthreads();
  }
  if (threadIdx.x == 0) *flag = (acc[0] != 0) ? 1u : 0u;
}

__global__ __launch_bounds__(256) void zero_k(float* __restrict__ p) {
  p[blockIdx.x * 256 + threadIdx.x] = 0.f;
}

// ---- canonicalize biases -> fp32 --------------------------------------------
__global__ __launch_bounds__(256) void canon_b_k(const void* b1, const void* b2,
                                                 const void* b3,
                                                 float* __restrict__ dst,
                                                 const uint32_t* __restrict__ flag) {
  const void* src = (blockIdx.x == 0) ? b1 : (blockIdx.x == 1) ? b2 : b3;
  float* d = dst + blockIdx.x * 1024;
  const bool isbf = (*flag != 0);
  for (int i = threadIdx.x; i < 1024; i += 256)
    d[i] = isbf ? bf2f(((const ushort*)src)[i]) : ((const float*)src)[i];
}

// ---- canonicalize + transpose 1024x1024 -> bf16 D[n][k] ---------------------
__global__ __launch_bounds__(256) void canon_w_k(const void* __restrict__ S,
                                                 ushort* __restrict__ D,
                                                 const uint32_t* __restrict__ flag) {
  __shared__ ushort tile[32][33];
  const int bx = blockIdx.x * 32, by = blockIdx.y * 32;
  const int tx = threadIdx.x, ty = threadIdx.y;  // (32,8)
  const bool isbf = (*flag != 0);
  #pragma unroll
  for (int i = 0; i < 32; i += 8) {
    const size_t idx = (size_t)(by + ty + i) * 1024 + bx + tx;
    tile[ty + i][tx] = isbf ? ((const ushort*)S)[idx] : f2bf(((const float*)S)[idx]);
  }
  __syncthreads();
  #pragma unroll
  for (int i = 0; i < 32; i += 8)
    D[(size_t)(bx + ty + i) * 1024 + by + tx] = tile[tx][ty + i];
}

// ---- bit trajectory: signs[t][m] = bit value BEFORE flip at step t ----------
__global__ __launch_bounds__(256) void sign_k(const void* __restrict__ init,
                                              const int* __restrict__ tpos,
                                              uint8_t* __restrict__ signs,
                                              const uint32_t* __restrict__ flag) {
  const int m = blockIdx.x, tid = threadIdx.x;
  const bool isbf = (*flag != 0);
  __shared__ float bits[NDIM];
  #pragma unroll
  for (int i = 0; i < 4; ++i) {
    const int k = tid + i * 256;
    bits[k] = isbf ? bf2f(((const ushort*)init)[(size_t)m * NDIM + k])
                   : ((const float*)init)[(size_t)m * NDIM + k];
  }
  __syncthreads();
  if (tid == 0) {
    for (int t = 0; t < TSTEPS; ++t) {
      const int tp = tpos[t * BATCH + m];
      const float b = bits[tp];
      signs[t * BATCH + m] = (uint8_t)(b != 0.f);
      bits[tp] = 1.f - b;
    }
  }
}

// ======================= FAST PATH: 128x128 m97-style GEMM ===================
// C[M,1024] = A[M,1024] @ Bt^T (+bias).  Bt is bf16 [n][k] (pre-transposed).
// ASTAGE 0: A bf16 via global_load_lds.  1: A raw (init) via flag VGPR staging.
// EPI 0: fp32 store.  1: relu bf16 store.  2: softmax partials (rowbase).
template <int ASTAGE, int EPI>
__global__ __launch_bounds__(256) void gemm_bt(const void* __restrict__ A,
                                               const ushort* __restrict__ Bt,
                                               const float* __restrict__ bias,
                                               void* __restrict__ Cout,
                                               const int* __restrict__ tpos,
                                               float* __restrict__ rowsum,
                                               float* __restrict__ tgt,
                                               const uint32_t* __restrict__ flag,
                                               int rowbase) {
  constexpr int BM = 128, BN = 128, BK = 32, K = 1024;
  __shared__ ushort Asm[BM * BK];   // 8 KB
  __shared__ ushort Bsm[BN * BK];   // 8 KB
  const int tid = threadIdx.x;
  const int wave = tid >> 6, lane = tid & 63;
  const int q = lane >> 4, r = lane & 15;
  const int n0 = blockIdx.x * BN;   // 8 n-blocks (fastest -> A-band L2 reuse)
  const int m0 = blockIdx.y * BM;
  const int wm = (wave & 1) * 64, wn = (wave >> 1) * 64;

  f32x4 acc[4][4];
  #pragma unroll
  for (int i = 0; i < 4; ++i)
    #pragma unroll
    for (int j = 0; j < 4; ++j)
      #pragma unroll
      for (int e = 0; e < 4; ++e) acc[i][j][e] = 0.f;

  const int f0 = tid * 16, f1 = f0 + 4096;     // byte offsets in 8 KB tile
  const int row0 = f0 >> 6, kb0 = f0 & 63;     // 64 B per row (BK=32 bf16)
  const int row1 = f1 >> 6, kb1 = f1 & 63;
  const bool isbf = (ASTAGE == 1) ? (*flag != 0) : true;

  for (int k0 = 0; k0 < K; k0 += BK) {
    if constexpr (ASTAGE == 0) {
      gload_lds16((const char*)A + ((size_t)(m0 + row0) * K + k0) * 2 + kb0, (char*)Asm + f0);
      gload_lds16((const char*)A + ((size_t)(m0 + row1) * K + k0) * 2 + kb1, (char*)Asm + f1);
    } else {
      u16x8 a0, a1v;
      const int e0 = kb0 >> 1, e1 = kb1 >> 1;
      if (isbf) {
        a0  = *(const u16x8*)((const ushort*)A + (size_t)(m0 + row0) * K + k0 + e0);
        a1v = *(const u16x8*)((const ushort*)A + (size_t)(m0 + row1) * K + k0 + e1);
      } else {
        const float* p0 = (const float*)A + (size_t)(m0 + row0) * K + k0 + e0;
        const float* p1 = (const float*)A + (size_t)(m0 + row1) * K + k0 + e1;
        const float4 fa = *(const float4*)p0, fb = *(const float4*)(p0 + 4);
        const float4 fc = *(const float4*)p1, fd = *(const float4*)(p1 + 4);
        a0[0] = f2bf(fa.x); a0[1] = f2bf(fa.y); a0[2] = f2bf(fa.z); a0[3] = f2bf(fa.w);
        a0[4] = f2bf(fb.x); a0[5] = f2bf(fb.y); a0[6] = f2bf(fb.z); a0[7] = f2bf(fb.w);
        a1v[0] = f2bf(fc.x); a1v[1] = f2bf(fc.y); a1v[2] = f2bf(fc.z); a1v[3] = f2bf(fc.w);
        a1v[4] = f2bf(fd.x); a1v[5] = f2bf(fd.y); a1v[6] = f2bf(fd.z); a1v[7] = f2bf(fd.w);
      }
      *(u16x8*)((char*)Asm + f0) = a0;
      *(u16x8*)((char*)Asm + f1) = a1v;
    }
    gload_lds16((const char*)Bt + ((size_t)(n0 + row0) * K + k0) * 2 + kb0, (char*)Bsm + f0);
    gload_lds16((const char*)Bt + ((size_t)(n0 + row1) * K + k0) * 2 + kb1, (char*)Bsm + f1);
    __syncthreads();
    bf16x8 af[4], bfr[4];
    #pragma unroll
    for (int t = 0; t < 4; ++t) {
      af[t]  = *(const bf16x8*)(Asm + (wm + t * 16 + r) * BK + q * 8);
      bfr[t] = *(const bf16x8*)(Bsm + (wn + t * 16 + r) * BK + q * 8);
    }
    #pragma unroll
    for (int mt = 0; mt < 4; ++mt)
      #pragma unroll
      for (int nt = 0; nt < 4; ++nt)
        acc[mt][nt] = __builtin_amdgcn_mfma_f32_16x16x32_bf16(af[mt], bfr[nt], acc[mt][nt], 0, 0, 0);
    __syncthreads();
  }

  #pragma unroll
  for (int mt = 0; mt < 4; ++mt) {
    #pragma unroll
    for (int reg = 0; reg < 4; ++reg) {
      const int grow = m0 + wm + mt * 16 + q * 4 + reg;
      if constexpr (EPI == 2) {
        const int growg = rowbase + grow;
        const int tp = tpos[growg];
        float s = 0.f;
        #pragma unroll
        for (int nt = 0; nt < 4; ++nt) {
          const int gcol = n0 + wn + nt * 16 + r;
          const float v = acc[mt][nt][reg] + bias[gcol];
          if (gcol == tp) tgt[growg] = v;
          s += __expf(v);
        }
        s += __shfl_xor(s, 1);
        s += __shfl_xor(s, 2);
        s += __shfl_xor(s, 4);
        s += __shfl_xor(s, 8);
        if (r == 0) atomicAdd(&rowsum[growg], s);
      } else {
        #pragma unroll
        for (int nt = 0; nt < 4; ++nt) {
          const int gcol = n0 + wn + nt * 16 + r;
          const float v = acc[mt][nt][reg] + bias[gcol];
          if constexpr (EPI == 0) {
            ((float*)Cout)[(size_t)grow * NDIM + gcol] = v;
          } else {
            ((ushort*)Cout)[(size_t)grow * NDIM + gcol] = f2bf(v > 0.f ? v : 0.f);
          }
        }
      }
    }
  }
}

// ---- h1 chunk: fp32 a1 recurrence + relu -> bf16 [CH*2048,1024] -------------
__global__ __launch_bounds__(256) void build_h1(float* __restrict__ a1,
                                                const void* __restrict__ W1,
                                                const uint8_t* __restrict__ signs,
                                                const int* __restrict__ tpos,
                                                ushort* __restrict__ h1,
                                                const uint32_t* __restrict__ flag,
                                                int t0, int nsteps) {
  const int m = blockIdx.x;
  const int k = threadIdx.x * 4;
  const bool isbf = (*flag != 0);
  float4 a = *(const float4*)(a1 + (size_t)m * HID + k);
  for (int t = 0; t < nsteps; ++t) {
    ushort4 h;
    h.x = f2bf(a.x > 0.f ? a.x : 0.f);
    h.y = f2bf(a.y > 0.f ? a.y : 0.f);
    h.z = f2bf(a.z > 0.f ? a.z : 0.f);
    h.w = f2bf(a.w > 0.f ? a.w : 0.f);
    *(ushort4*)(h1 + ((size_t)(t * BATCH + m)) * HID + k) = h;   // chunk-local row
    const int tg = t0 + t;
    const int tp = tpos[tg * BATCH + m];
    const float s = 1.f - 2.f * (float)signs[tg * BATCH + m];
    float wx, wy, wz, ww;
    if (isbf) {
      const ushort4 wv = *(const ushort4*)((const ushort*)W1 + (size_t)tp * HID + k);
      wx = bf2f(wv.x); wy = bf2f(wv.y); wz = bf2f(wv.z); ww = bf2f(wv.w);
    } else {
      const float4 wv = *(const float4*)((const float*)W1 + (size_t)tp * HID + k);
      wx = wv.x; wy = wv.y; wz = wv.z; ww = wv.w;
    }
    a.x += s * wx; a.y += s * wy; a.z += s * wz; a.w += s * ww;
  }
  *(float4*)(a1 + (size_t)m * HID + k) = a;   // carry to next chunk
}

// ---- total_log over all 32 steps -> d_out -----------------------------------
__global__ __launch_bounds__(256) void fin_total_k(const float* __restrict__ tgt,
                                                   const float* __restrict__ rowsum,
                                                   float* __restrict__ out_total) {
  const int m = blockIdx.x * 256 + threadIdx.x;
  float acc = 0.f;
  for (int t = 0; t < TSTEPS; ++t) {
    const int rr = t * BATCH + m;
    acc += tgt[rr] - logf(rowsum[rr]);
  }
  out_total[m] = acc;
}

// ======================= FALLBACK PATH (R8, verified green) ==================
template <int ASRC, int EPI>
__global__ __launch_bounds__(256) void gemm_t(const void* __restrict__ A,
                                              const void* __restrict__ W,
                                              const float* __restrict__ bias,
                                              ushort* __restrict__ Cout,
                                              const int* __restrict__ tpos,
                                              float* __restrict__ rowsum,
                                              float* __restrict__ tgt,
                                              const uint32_t* __restrict__ flag,
                                              int tstep) {
  constexpr int BM = 64, BN = 64, BK = 32, BKP = 40, K = 1024;
  __shared__ ushort Asm[BM * BKP];
  __shared__ ushort Bsm[BN * BKP];
  const int tid = threadIdx.x;
  const int w = tid >> 6, lane = tid & 63;
  const int q = lane >> 4, r = lane & 15;
  const int n0 = blockIdx.x * BN;
  const int m0 = blockIdx.y * BM;
  const bool isbf = (*flag != 0);
  const int srow = tid >> 2, scol = (tid & 3) * 8;
  const int kk = tid >> 3, ng = (tid & 7) * 8;

  f32x4 acc[4];
  #pragma unroll
  for (int nt = 0; nt < 4; ++nt)
    #pragma unroll
    for (int e = 0; e < 4; ++e) acc[nt][e] = 0.f;

  for (int k0 = 0; k0 < K; k0 += BK) {
    u16x8 av;
    if constexpr (ASRC == 0) {
      if (isbf) {
        av = *(const u16x8*)((const ushort*)A + (size_t)(m0 + srow) * K + k0 + scol);
      } else {
        const float* fp = (const float*)A + (size_t)(m0 + srow) * K + k0 + scol;
        const float4 fa = *(const float4*)fp, fb = *(const float4*)(fp + 4);
        av[0] = f2bf(fa.x); av[1] = f2bf(fa.y); av[2] = f2bf(fa.z); av[3] = f2bf(fa.w);
        av[4] = f2bf(fb.x); av[5] = f2bf(fb.y); av[6] = f2bf(fb.z); av[7] = f2bf(fb.w);
      }
    } else {
      av = *(const u16x8*)((const ushort*)A + (size_t)(m0 + srow) * K + k0 + scol);
      if constexpr (ASRC == 1) {
        #pragma unroll
        for (int e = 0; e < 8; ++e) av[e] = (av[e] & 0x8000u) ? (unsigned short)0 : av[e];
      }
    }
    ushort bw[8];
    if (isbf) {
      const u16x8 wv = *(const u16x8*)((const ushort*)W + (size_t)(k0 + kk) * NDIM + n0 + ng);
      #pragma unroll
      for (int j = 0; j < 8; ++j) bw[j] = wv[j];
    } else {
      const float* fp = (const float*)W + (size_t)(k0 + kk) * NDIM + n0 + ng;
      const float4 fa = *(const float4*)fp, fb = *(const float4*)(fp + 4);
      bw[0] = f2bf(fa.x); bw[1] = f2bf(fa.y); bw[2] = f2bf(fa.z); bw[3] = f2bf(fa.w);
      bw[4] = f2bf(fb.x); bw[5] = f2bf(fb.y); bw[6] = f2bf(fb.z); bw[7] = f2bf(fb.w);
    }
    __syncthreads();
    *(u16x8*)(Asm + srow * BKP + scol) = av;
    #pragma unroll
    for (int j = 0; j < 8; ++j) Bsm[(ng + j) * BKP + kk] = bw[j];
    __syncthreads();
    const bf16x8 af = *(const bf16x8*)(Asm + (w * 16 + r) * BKP + q * 8);
    #pragma unroll
    for (int nt = 0; nt < 4; ++nt) {
      const bf16x8 bfr = *(const bf16x8*)(Bsm + (nt * 16 + r) * BKP + q * 8);
      acc[nt] = __builtin_amdgcn_mfma_f32_16x16x32_bf16(af, bfr, acc[nt], 0, 0, 0);
    }
  }

  if constexpr (EPI == 2) {
    #pragma unroll
    for (int reg = 0; reg < 4; ++reg) {
      const int grow = m0 + w * 16 + q * 4 + reg;
      const int tp = tpos[tstep * BATCH + grow];
      float s = 0.f;
      #pragma unroll
      for (int nt = 0; nt < 4; ++nt) {
        const int gcol = n0 + nt * 16 + r;
        const float v = acc[nt][reg] + bias[gcol];
        if (gcol == tp) tgt[grow] = v;
        s += __expf(v);
      }
      s += __shfl_xor(s, 1);
      s += __shfl_xor(s, 2);
      s += __shfl_xor(s, 4);
      s += __shfl_xor(s, 8);
      if (r == 0) atomicAdd(&rowsum[grow], s);
    }
  } else {
    #pragma unroll
    for (int nt = 0; nt < 4; ++nt) {
      #pragma unroll
      for (int reg = 0; reg < 4; ++reg) {
        const int grow = m0 + w * 16 + q * 4 + reg;
        const int gcol = n0 + nt * 16 + r;
        float v = acc[nt][reg] + bias[gcol];
        if constexpr (EPI == 1) v = (v > 0.f) ? v : 0.f;
        Cout[(size_t)grow * NDIM + gcol] = f2bf(v);
      }
    }
  }
}

__global__ __launch_bounds__(256) void step_k(ushort* __restrict__ a1,
                                              const void* __restrict__ init,
                                              const void* __restrict__ W1,
                                              const int* __restrict__ tpos,
                                              float* __restrict__ rowsum,
                                              const float* __restrict__ tgt,
                                              float* __restrict__ total,
                                              const uint32_t* __restrict__ flag,
                                              int t) {
  const int m = blockIdx.x;
  const int k = threadIdx.x * 4;
  const bool isbf = (*flag != 0);
  const int tp = tpos[t * BATCH + m];
  const float b0 = isbf ? bf2f(((const ushort*)init)[(size_t)m * NDIM + tp])
                        : ((const float*)init)[(size_t)m * NDIM + tp];
  int cnt = 0;
  for (int u = 0; u < t; ++u) cnt += (tpos[u * BATCH + m] == tp) ? 1 : 0;
  const float bit = (cnt & 1) ? (1.f - b0) : b0;
  const float s = 1.f - 2.f * bit;
  float wx, wy, wz, ww;
  if (isbf) {
    const ushort4 wv = *(const ushort4*)((const ushort*)W1 + (size_t)tp * HID + k);
    wx = bf2f(wv.x); wy = bf2f(wv.y); wz = bf2f(wv.z); ww = bf2f(wv.w);
  } else {
    const float4 wv = *(const float4*)((const float*)W1 + (size_t)tp * HID + k);
    wx = wv.x; wy = wv.y; wz = wv.z; ww = wv.w;
  }
  ushort4 a = *(const ushort4*)(a1 + (size_t)m * HID + k);
  a.x = f2bf(bf2f(a.x) + s * wx);
  a.y = f2bf(bf2f(a.y) + s * wy);
  a.z = f2bf(bf2f(a.z) + s * wz);
  a.w = f2bf(bf2f(a.w) + s * ww);
  *(ushort4*)(a1 + (size_t)m * HID + k) = a;
  if (threadIdx.x == 0) {
    total[m] += tgt[m] - logf(rowsum[m]);
    rowsum[m] = 0.f;
  }
}

__global__ __launch_bounds__(256) void finalize_k(const float* __restrict__ total,
                                                  float* __restrict__ out_total) {
  const int m = blockIdx.x * 256 + threadIdx.x;
  out_total[m] = total[m];
}

// ======================= shared output kernels (fp32) ========================
__global__ __launch_bounds__(256) void out_final_k(const void* __restrict__ init,
                                                   const int* __restrict__ tpos,
                                                   float* __restrict__ out,
                                                   const uint32_t* __restrict__ flag) {
  const int m = blockIdx.x;
  const int k = threadIdx.x * 4;
  const bool isbf = (*flag != 0);
  float v[4];
  if (isbf) {
    const ushort4 iv = *(const ushort4*)((const ushort*)init + (size_t)m * NDIM + k);
    v[0] = bf2f(iv.x); v[1] = bf2f(iv.y); v[2] = bf2f(iv.z); v[3] = bf2f(iv.w);
  } else {
    const float4 iv = *(const float4*)((const float*)init + (size_t)m * NDIM + k);
    v[0] = iv.x; v[1] = iv.y; v[2] = iv.z; v[3] = iv.w;
  }
  for (int t = 0; t < TSTEPS; ++t) {
    const int tp = tpos[t * BATCH + m];
    if ((tp >> 2) == (int)threadIdx.x) v[tp & 3] = 1.f - v[tp & 3];
  }
  float4 o; o.x = v[0]; o.y = v[1]; o.z = v[2]; o.w = v[3];
  *(float4*)(out + OUT_FINAL + (size_t)m * NDIM + k) = o;
}

__global__ __launch_bounds__(256) void out_vinit_k(const void* __restrict__ init,
                                                   float* __restrict__ out,
                                                   const uint32_t* __restrict__ flag) {
  const int i = (blockIdx.x * 256 + threadIdx.x) * 4;
  float4 o;
  if (*flag) {
    const ushort4 iv = *(const ushort4*)((const ushort*)init + i);
    o.x = bf2f(iv.x); o.y = bf2f(iv.y); o.z = bf2f(iv.z); o.w = bf2f(iv.w);
  } else {
    o = *(const float4*)((const float*)init + i);
  }
  *(float4*)(out + OUT_VINIT + i) = o;
}

__global__ __launch_bounds__(256) void out_delta_k(const int* __restrict__ tpos,
                                                   float* __restrict__ out) {
  const int i = blockIdx.x * 256 + threadIdx.x;
  out[OUT_DELTA + i] = (float)tpos[i];
}

extern "C" void kernel_launch(void* const* d_in, const int* in_sizes, int n_in,
                              void* d_out, int out_size, void* d_ws, size_t ws_size,
                              hipStream_t stream) {
  const void* init = d_in[0];
  const int* tpos  = (const int*)d_in[1];
  const void* W1 = d_in[2];
  const void* b1 = d_in[3];
  const void* W2 = d_in[4];
  const void* b2 = d_in[5];
  const void* W3 = d_in[6];
  const void* b3 = d_in[7];
  float* out = (float*)d_out;
  char* ws = (char*)d_ws;

  const size_t MB = 1024ull * 1024ull;
  int CH = TSTEPS;
  while (CH > 1 && (size_t)WF_H1 + (size_t)CH * 8 * MB > ws_size) CH >>= 1;
  const bool fast = (ws_size >= (size_t)WF_H1 + 8 * MB);

  if (fast) {
    ushort*   WT1    = (ushort*)(ws + WF_WT1);
    ushort*   WT2    = (ushort*)(ws + WF_WT2);
    ushort*   WT3    = (ushort*)(ws + WF_WT3);
    float*    a1f    = (float*)(ws + WF_A1);
    float*    biases = (float*)(ws + WF_BIAS);
    uint8_t*  signs  = (uint8_t*)(ws + WF_SIGNS);
    float*    rowsum = (float*)(ws + WF_ROWSUM);
    float*    tgt    = (float*)(ws + WF_TGT);
    uint32_t* flag   = (uint32_t*)(ws + WF_FLAG);
    ushort*   h1     = (ushort*)(ws + WF_H1);
    ushort*   h2     = (ushort*)(ws + WF_H1 + (size_t)CH * 4 * MB);

    flag_k<<<1, 256, 0, stream>>>(init, flag);
    canon_b_k<<<3, 256, 0, stream>>>(b1, b2, b3, biases, flag);
    canon_w_k<<<dim3(32, 32), dim3(32, 8), 0, stream>>>(W1, WT1, flag);
    canon_w_k<<<dim3(32, 32), dim3(32, 8), 0, stream>>>(W2, WT2, flag);
    canon_w_k<<<dim3(32, 32), dim3(32, 8), 0, stream>>>(W3, WT3, flag);
    sign_k<<<BATCH, 256, 0, stream>>>(init, tpos, signs, flag);
    zero_k<<<512, 256, 0, stream>>>(rowsum);   // rowsum|tgt contiguous 131072 f32

    // a1 = init @ W1 + b1  (fp32 out)
    gemm_bt<1, 0><<<dim3(8, 16), 256, 0, stream>>>(init, WT1, biases + 0, a1f,
                                                   nullptr, nullptr, nullptr, flag, 0);

    for (int t0 = 0; t0 < TSTEPS; t0 += CH) {
      build_h1<<<BATCH, 256, 0, stream>>>(a1f, W1, signs, tpos, h1, flag, t0, CH);
      // h2 = relu(h1 @ W2 + b2)   (M = CH*2048)
      gemm_bt<0, 1><<<dim3(8, CH * 16), 256, 0, stream>>>(h1, WT2, biases + 1024, h2,
                                                          nullptr, nullptr, nullptr, flag, 0);
      // logits = h2 @ W3 + b3 -> softmax partials
      gemm_bt<0, 2><<<dim3(8, CH * 16), 256, 0, stream>>>(h2, WT3, biases + 2048, nullptr,
                                                          tpos, rowsum, tgt, flag, t0 * BATCH);
    }
    fin_total_k<<<8, 256, 0, stream>>>(tgt, rowsum, out + OUT_TOTAL);
    out_final_k<<<BATCH, 256, 0, stream>>>(init, tpos, out, flag);
    out_vinit_k<<<2048, 256, 0, stream>>>(init, out, flag);
    out_delta_k<<<256, 256, 0, stream>>>(tpos, out);
  } else {
    // -------- fallback: R8 verified d_out-resident path --------
    ushort*   a1     = (ushort*)(out + OUT_FINAL);
    ushort*   h2     = (ushort*)(out + OUT_VINIT);
    char*     sc     = (char*)(out + OUT_DELTA);
    float*    rowsum = (float*)(sc + SC_ROWSUM);
    float*    tgt    = (float*)(sc + SC_TGT);
    float*    total  = (float*)(sc + SC_TOTAL);
    float*    biases = (float*)(sc + SC_BIAS);
    uint32_t* flag   = (uint32_t*)(sc + SC_FLAG);

    flag_k<<<1, 256, 0, stream>>>(init, flag);
    zero_k<<<24, 256, 0, stream>>>(rowsum);
    canon_b_k<<<3, 256, 0, stream>>>(b1, b2, b3, biases, flag);
    gemm_t<0, 0><<<dim3(16, 32), 256, 0, stream>>>(init, W1, biases + 0, a1,
                                                   nullptr, nullptr, nullptr, flag, 0);
    for (int t = 0; t < TSTEPS; ++t) {
      gemm_t<1, 1><<<dim3(16, 32), 256, 0, stream>>>(a1, W2, biases + 1024, h2,
                                                     nullptr, nullptr, nullptr, flag, 0);
      gemm_t<2, 2><<<dim3(16, 32), 256, 0, stream>>>(h2, W3, biases + 2048, nullptr,
                                                     tpos, rowsum, tgt, flag, t);
      step_k<<<BATCH, 256, 0, stream>>>(a1, init, W1, tpos, rowsum, tgt, total, flag, t);
    }
    finalize_k<<<8, 256, 0, stream>>>(total, out + OUT_TOTAL);
    out_final_k<<<BATCH, 256, 0, stream>>>(init, tpos, out, flag);
    out_vinit_k<<<2048, 256, 0, stream>>>(init, out, flag);
    out_delta_k<<<256, 256, 0, stream>>>(tpos, out);
  }
}

// Round 10
// 606.247 us; speedup vs baseline: 4.4176x; 1.0752x over previous
//
#include <hip/hip_runtime.h>
#include <stdint.h>

#define BATCH 2048
#define NDIM  1024
#define HID   1024
#define TSTEPS 32

// out layout (FP32 elems): final[2048*1024] | delta[32*2048] | total[2048] | vinit[2048*1024]
#define OUT_FINAL 0
#define OUT_DELTA 2097152
#define OUT_TOTAL 2162688
#define OUT_VINIT 2164736

// ---- fallback-path scratch inside the delta region (bytes from out+OUT_DELTA)
#define SC_ROWSUM 0        // 2048 f32
#define SC_TGT    8192     // 2048 f32
#define SC_TOTAL  16384    // 2048 f32
#define SC_BIAS   24576    // 3072 f32
#define SC_FLAG   36864    // u32

// ---- fast-path d_ws layout (bytes) ----
#define WF_WT1    0u           // 2 MB  W1^T bf16 [n][k]
#define WF_WT2    2097152u     // 2 MB
#define WF_WT3    4194304u     // 2 MB
#define WF_A1     6291456u     // 8 MB  fp32 a1 carry [2048][1024]
#define WF_BIAS   14680064u    // 12 KB fp32 b1|b2|b3
#define WF_SIGNS  14692352u    // 64 KB u8 bit-before-flip per (t,m)
#define WF_ROWSUM 14757888u    // 256 KB fp32[65536]
#define WF_TGT    15020032u    // 256 KB fp32[65536]
#define WF_FLAG   15282176u    // 4 B
#define WF_H1     15286272u    // CH*4 MB bf16
// h2 follows h1: CH*4 MB

__device__ __forceinline__ float bf2f(ushort u) {
  union { uint32_t u; float f; } v; v.u = ((uint32_t)u) << 16; return v.f;
}
__device__ __forceinline__ ushort f2bf(float f) {
  union { float f; uint32_t u; } v; v.f = f;
  uint32_t u = v.u;
  u += 0x7fffu + ((u >> 16) & 1u);   // RNE
  return (ushort)(u >> 16);
}

typedef __attribute__((ext_vector_type(8))) short bf16x8;
typedef __attribute__((ext_vector_type(8))) unsigned short u16x8;
typedef __attribute__((ext_vector_type(4))) float f32x4;

__device__ __forceinline__ void gload_lds16(const void* g, void* l) {
  __builtin_amdgcn_global_load_lds((const __attribute__((address_space(1))) void*)g,
                                   (__attribute__((address_space(3))) void*)l, 16, 0, 0);
}

// ---- dtype flag: bf16 iff any even-index ushort of first 64K ushorts != 0 ---
__global__ __launch_bounds__(256) void flag_k(const void* __restrict__ init,
                                              uint32_t* __restrict__ flag) {
  const ushort* p = (const ushort*)init;
  __shared__ uint32_t acc[256];
  uint32_t a = 0;
  for (int i = threadIdx.x; i < 32768; i += 256) a |= p[2 * i];
  acc[threadIdx.x] = a;
  __syncthreads();
  for (int s = 128; s > 0; s >>= 1) {
    if (threadIdx.x < s) acc[threadIdx.x] |= acc[threadIdx.x + s];
    __syncthreads();
  }
  if (threadIdx.x == 0) *flag = (acc[0] != 0) ? 1u : 0u;
}

__global__ __launch_bounds__(256) void zero_k(float* __restrict__ p) {
  p[blockIdx.x * 256 + threadIdx.x] = 0.f;
}

// ---- canonicalize biases -> fp32 --------------------------------------------
__global__ __launch_bounds__(256) void canon_b_k(const void* b1, const void* b2,
                                                 const void* b3,
                                                 float* __restrict__ dst,
                                                 const uint32_t* __restrict__ flag) {
  const void* src = (blockIdx.x == 0) ? b1 : (blockIdx.x == 1) ? b2 : b3;
  float* d = dst + blockIdx.x * 1024;
  const bool isbf = (*flag != 0);
  for (int i = threadIdx.x; i < 1024; i += 256)
    d[i] = isbf ? bf2f(((const ushort*)src)[i]) : ((const float*)src)[i];
}

// ---- canonicalize + transpose 1024x1024 -> bf16 D[n][k] ---------------------
__global__ __launch_bounds__(256) void canon_w_k(const void* __restrict__ S,
                                                 ushort* __restrict__ D,
                                                 const uint32_t* __restrict__ flag) {
  __shared__ ushort tile[32][33];
  const int bx = blockIdx.x * 32, by = blockIdx.y * 32;
  const int tx = threadIdx.x, ty = threadIdx.y;  // (32,8)
  const bool isbf = (*flag != 0);
  #pragma unroll
  for (int i = 0; i < 32; i += 8) {
    const size_t idx = (size_t)(by + ty + i) * 1024 + bx + tx;
    tile[ty + i][tx] = isbf ? ((const ushort*)S)[idx] : f2bf(((const float*)S)[idx]);
  }
  __syncthreads();
  #pragma unroll
  for (int i = 0; i < 32; i += 8)
    D[(size_t)(bx + ty + i) * 1024 + by + tx] = tile[tx][ty + i];
}

// ---- bit trajectory: signs[t][m] = bit value BEFORE flip at step t ----------
__global__ __launch_bounds__(256) void sign_k(const void* __restrict__ init,
                                              const int* __restrict__ tpos,
                                              uint8_t* __restrict__ signs,
                                              const uint32_t* __restrict__ flag) {
  const int m = blockIdx.x, tid = threadIdx.x;
  const bool isbf = (*flag != 0);
  __shared__ float bits[NDIM];
  #pragma unroll
  for (int i = 0; i < 4; ++i) {
    const int k = tid + i * 256;
    bits[k] = isbf ? bf2f(((const ushort*)init)[(size_t)m * NDIM + k])
                   : ((const float*)init)[(size_t)m * NDIM + k];
  }
  __syncthreads();
  if (tid == 0) {
    for (int t = 0; t < TSTEPS; ++t) {
      const int tp = tpos[t * BATCH + m];
      const float b = bits[tp];
      signs[t * BATCH + m] = (uint8_t)(b != 0.f);
      bits[tp] = 1.f - b;
    }
  }
}

// ======================= FAST PATH: 128x128 m97-style GEMM ===================
// C[M,1024] = A[M,1024] @ Bt^T (+bias).  Bt is bf16 [n][k] (pre-transposed).
// XCD-aware swizzle: workgroup->XCD is round-robin on dispatch index, so remap
// (mb,nb) such that all 8 n-blocks sharing an A-band get the same lid%8 (same
// XCD L2) in consecutive per-XCD slots. Requires gridDim.y % 8 == 0.
// ASTAGE 0: A bf16 via global_load_lds.  1: A raw (init) via flag VGPR staging.
// EPI 0: fp32 store.  1: relu bf16 store.  2: softmax partials (rowbase).
template <int ASTAGE, int EPI>
__global__ __launch_bounds__(256) void gemm_bt(const void* __restrict__ A,
                                               const ushort* __restrict__ Bt,
                                               const float* __restrict__ bias,
                                               void* __restrict__ Cout,
                                               const int* __restrict__ tpos,
                                               float* __restrict__ rowsum,
                                               float* __restrict__ tgt,
                                               const uint32_t* __restrict__ flag,
                                               int rowbase) {
  constexpr int BM = 128, BN = 128, BK = 32, K = 1024;
  __shared__ ushort Asm[BM * BK];   // 8 KB
  __shared__ ushort Bsm[BN * BK];   // 8 KB
  const int tid = threadIdx.x;
  const int wave = tid >> 6, lane = tid & 63;
  const int q = lane >> 4, r = lane & 15;

  // ---- XCD-aware (mb, nb) swizzle ----
  const int lid = blockIdx.y * gridDim.x + blockIdx.x;  // dispatch order (x fastest)
  const int xcd = lid & 7;
  const int s   = lid >> 3;              // per-XCD slot
  const int mb  = xcd + 8 * (s >> 3);    // A-band owned by this XCD
  const int nb  = s & 7;                 // n-block within the band
  const int n0 = nb * BN;
  const int m0 = mb * BM;
  const int wm = (wave & 1) * 64, wn = (wave >> 1) * 64;

  f32x4 acc[4][4];
  #pragma unroll
  for (int i = 0; i < 4; ++i)
    #pragma unroll
    for (int j = 0; j < 4; ++j)
      #pragma unroll
      for (int e = 0; e < 4; ++e) acc[i][j][e] = 0.f;

  const int f0 = tid * 16, f1 = f0 + 4096;     // byte offsets in 8 KB tile
  const int row0 = f0 >> 6, kb0 = f0 & 63;     // 64 B per row (BK=32 bf16)
  const int row1 = f1 >> 6, kb1 = f1 & 63;
  const bool isbf = (ASTAGE == 1) ? (*flag != 0) : true;

  for (int k0 = 0; k0 < K; k0 += BK) {
    if constexpr (ASTAGE == 0) {
      gload_lds16((const char*)A + ((size_t)(m0 + row0) * K + k0) * 2 + kb0, (char*)Asm + f0);
      gload_lds16((const char*)A + ((size_t)(m0 + row1) * K + k0) * 2 + kb1, (char*)Asm + f1);
    } else {
      u16x8 a0, a1v;
      const int e0 = kb0 >> 1, e1 = kb1 >> 1;
      if (isbf) {
        a0  = *(const u16x8*)((const ushort*)A + (size_t)(m0 + row0) * K + k0 + e0);
        a1v = *(const u16x8*)((const ushort*)A + (size_t)(m0 + row1) * K + k0 + e1);
      } else {
        const float* p0 = (const float*)A + (size_t)(m0 + row0) * K + k0 + e0;
        const float* p1 = (const float*)A + (size_t)(m0 + row1) * K + k0 + e1;
        const float4 fa = *(const float4*)p0, fb = *(const float4*)(p0 + 4);
        const float4 fc = *(const float4*)p1, fd = *(const float4*)(p1 + 4);
        a0[0] = f2bf(fa.x); a0[1] = f2bf(fa.y); a0[2] = f2bf(fa.z); a0[3] = f2bf(fa.w);
        a0[4] = f2bf(fb.x); a0[5] = f2bf(fb.y); a0[6] = f2bf(fb.z); a0[7] = f2bf(fb.w);
        a1v[0] = f2bf(fc.x); a1v[1] = f2bf(fc.y); a1v[2] = f2bf(fc.z); a1v[3] = f2bf(fc.w);
        a1v[4] = f2bf(fd.x); a1v[5] = f2bf(fd.y); a1v[6] = f2bf(fd.z); a1v[7] = f2bf(fd.w);
      }
      *(u16x8*)((char*)Asm + f0) = a0;
      *(u16x8*)((char*)Asm + f1) = a1v;
    }
    gload_lds16((const char*)Bt + ((size_t)(n0 + row0) * K + k0) * 2 + kb0, (char*)Bsm + f0);
    gload_lds16((const char*)Bt + ((size_t)(n0 + row1) * K + k0) * 2 + kb1, (char*)Bsm + f1);
    __syncthreads();
    bf16x8 af[4], bfr[4];
    #pragma unroll
    for (int t = 0; t < 4; ++t) {
      af[t]  = *(const bf16x8*)(Asm + (wm + t * 16 + r) * BK + q * 8);
      bfr[t] = *(const bf16x8*)(Bsm + (wn + t * 16 + r) * BK + q * 8);
    }
    #pragma unroll
    for (int mt = 0; mt < 4; ++mt)
      #pragma unroll
      for (int nt = 0; nt < 4; ++nt)
        acc[mt][nt] = __builtin_amdgcn_mfma_f32_16x16x32_bf16(af[mt], bfr[nt], acc[mt][nt], 0, 0, 0);
    __syncthreads();
  }

  #pragma unroll
  for (int mt = 0; mt < 4; ++mt) {
    #pragma unroll
    for (int reg = 0; reg < 4; ++reg) {
      const int grow = m0 + wm + mt * 16 + q * 4 + reg;
      if constexpr (EPI == 2) {
        const int growg = rowbase + grow;
        const int tp = tpos[growg];
        float s2 = 0.f;
        #pragma unroll
        for (int nt = 0; nt < 4; ++nt) {
          const int gcol = n0 + wn + nt * 16 + r;
          const float v = acc[mt][nt][reg] + bias[gcol];
          if (gcol == tp) tgt[growg] = v;
          s2 += __expf(v);
        }
        s2 += __shfl_xor(s2, 1);
        s2 += __shfl_xor(s2, 2);
        s2 += __shfl_xor(s2, 4);
        s2 += __shfl_xor(s2, 8);
        if (r == 0) atomicAdd(&rowsum[growg], s2);
      } else {
        #pragma unroll
        for (int nt = 0; nt < 4; ++nt) {
          const int gcol = n0 + wn + nt * 16 + r;
          const float v = acc[mt][nt][reg] + bias[gcol];
          if constexpr (EPI == 0) {
            ((float*)Cout)[(size_t)grow * NDIM + gcol] = v;
          } else {
            ((ushort*)Cout)[(size_t)grow * NDIM + gcol] = f2bf(v > 0.f ? v : 0.f);
          }
        }
      }
    }
  }
}

// ---- h1 chunk: fp32 a1 recurrence + relu -> bf16 [CH*2048,1024] -------------
__global__ __launch_bounds__(256) void build_h1(float* __restrict__ a1,
                                                const void* __restrict__ W1,
                                                const uint8_t* __restrict__ signs,
                                                const int* __restrict__ tpos,
                                                ushort* __restrict__ h1,
                                                const uint32_t* __restrict__ flag,
                                                int t0, int nsteps) {
  const int m = blockIdx.x;
  const int k = threadIdx.x * 4;
  const bool isbf = (*flag != 0);
  float4 a = *(const float4*)(a1 + (size_t)m * HID + k);
  for (int t = 0; t < nsteps; ++t) {
    ushort4 h;
    h.x = f2bf(a.x > 0.f ? a.x : 0.f);
    h.y = f2bf(a.y > 0.f ? a.y : 0.f);
    h.z = f2bf(a.z > 0.f ? a.z : 0.f);
    h.w = f2bf(a.w > 0.f ? a.w : 0.f);
    *(ushort4*)(h1 + ((size_t)(t * BATCH + m)) * HID + k) = h;   // chunk-local row
    const int tg = t0 + t;
    const int tp = tpos[tg * BATCH + m];
    const float s = 1.f - 2.f * (float)signs[tg * BATCH + m];
    float wx, wy, wz, ww;
    if (isbf) {
      const ushort4 wv = *(const ushort4*)((const ushort*)W1 + (size_t)tp * HID + k);
      wx = bf2f(wv.x); wy = bf2f(wv.y); wz = bf2f(wv.z); ww = bf2f(wv.w);
    } else {
      const float4 wv = *(const float4*)((const float*)W1 + (size_t)tp * HID + k);
      wx = wv.x; wy = wv.y; wz = wv.z; ww = wv.w;
    }
    a.x += s * wx; a.y += s * wy; a.z += s * wz; a.w += s * ww;
  }
  *(float4*)(a1 + (size_t)m * HID + k) = a;   // carry to next chunk
}

// ---- total_log over all 32 steps -> d_out -----------------------------------
__global__ __launch_bounds__(256) void fin_total_k(const float* __restrict__ tgt,
                                                   const float* __restrict__ rowsum,
                                                   float* __restrict__ out_total) {
  const int m = blockIdx.x * 256 + threadIdx.x;
  float acc = 0.f;
  for (int t = 0; t < TSTEPS; ++t) {
    const int rr = t * BATCH + m;
    acc += tgt[rr] - logf(rowsum[rr]);
  }
  out_total[m] = acc;
}

// ======================= FALLBACK PATH (R8, verified green) ==================
template <int ASRC, int EPI>
__global__ __launch_bounds__(256) void gemm_t(const void* __restrict__ A,
                                              const void* __restrict__ W,
                                              const float* __restrict__ bias,
                                              ushort* __restrict__ Cout,
                                              const int* __restrict__ tpos,
                                              float* __restrict__ rowsum,
                                              float* __restrict__ tgt,
                                              const uint32_t* __restrict__ flag,
                                              int tstep) {
  constexpr int BM = 64, BN = 64, BK = 32, BKP = 40, K = 1024;
  __shared__ ushort Asm[BM * BKP];
  __shared__ ushort Bsm[BN * BKP];
  const int tid = threadIdx.x;
  const int w = tid >> 6, lane = tid & 63;
  const int q = lane >> 4, r = lane & 15;
  const int n0 = blockIdx.x * BN;
  const int m0 = blockIdx.y * BM;
  const bool isbf = (*flag != 0);
  const int srow = tid >> 2, scol = (tid & 3) * 8;
  const int kk = tid >> 3, ng = (tid & 7) * 8;

  f32x4 acc[4];
  #pragma unroll
  for (int nt = 0; nt < 4; ++nt)
    #pragma unroll
    for (int e = 0; e < 4; ++e) acc[nt][e] = 0.f;

  for (int k0 = 0; k0 < K; k0 += BK) {
    u16x8 av;
    if constexpr (ASRC == 0) {
      if (isbf) {
        av = *(const u16x8*)((const ushort*)A + (size_t)(m0 + srow) * K + k0 + scol);
      } else {
        const float* fp = (const float*)A + (size_t)(m0 + srow) * K + k0 + scol;
        const float4 fa = *(const float4*)fp, fb = *(const float4*)(fp + 4);
        av[0] = f2bf(fa.x); av[1] = f2bf(fa.y); av[2] = f2bf(fa.z); av[3] = f2bf(fa.w);
        av[4] = f2bf(fb.x); av[5] = f2bf(fb.y); av[6] = f2bf(fb.z); av[7] = f2bf(fb.w);
      }
    } else {
      av = *(const u16x8*)((const ushort*)A + (size_t)(m0 + srow) * K + k0 + scol);
      if constexpr (ASRC == 1) {
        #pragma unroll
        for (int e = 0; e < 8; ++e) av[e] = (av[e] & 0x8000u) ? (unsigned short)0 : av[e];
      }
    }
    ushort bw[8];
    if (isbf) {
      const u16x8 wv = *(const u16x8*)((const ushort*)W + (size_t)(k0 + kk) * NDIM + n0 + ng);
      #pragma unroll
      for (int j = 0; j < 8; ++j) bw[j] = wv[j];
    } else {
      const float* fp = (const float*)W + (size_t)(k0 + kk) * NDIM + n0 + ng;
      const float4 fa = *(const float4*)fp, fb = *(const float4*)(fp + 4);
      bw[0] = f2bf(fa.x); bw[1] = f2bf(fa.y); bw[2] = f2bf(fa.z); bw[3] = f2bf(fa.w);
      bw[4] = f2bf(fb.x); bw[5] = f2bf(fb.y); bw[6] = f2bf(fb.z); bw[7] = f2bf(fb.w);
    }
    __syncthreads();
    *(u16x8*)(Asm + srow * BKP + scol) = av;
    #pragma unroll
    for (int j = 0; j < 8; ++j) Bsm[(ng + j) * BKP + kk] = bw[j];
    __syncthreads();
    const bf16x8 af = *(const bf16x8*)(Asm + (w * 16 + r) * BKP + q * 8);
    #pragma unroll
    for (int nt = 0; nt < 4; ++nt) {
      const bf16x8 bfr = *(const bf16x8*)(Bsm + (nt * 16 + r) * BKP + q * 8);
      acc[nt] = __builtin_amdgcn_mfma_f32_16x16x32_bf16(af, bfr, acc[nt], 0, 0, 0);
    }
  }

  if constexpr (EPI == 2) {
    #pragma unroll
    for (int reg = 0; reg < 4; ++reg) {
      const int grow = m0 + w * 16 + q * 4 + reg;
      const int tp = tpos[tstep * BATCH + grow];
      float s = 0.f;
      #pragma unroll
      for (int nt = 0; nt < 4; ++nt) {
        const int gcol = n0 + nt * 16 + r;
        const float v = acc[nt][reg] + bias[gcol];
        if (gcol == tp) tgt[grow] = v;
        s += __expf(v);
      }
      s += __shfl_xor(s, 1);
      s += __shfl_xor(s, 2);
      s += __shfl_xor(s, 4);
      s += __shfl_xor(s, 8);
      if (r == 0) atomicAdd(&rowsum[grow], s);
    }
  } else {
    #pragma unroll
    for (int nt = 0; nt < 4; ++nt) {
      #pragma unroll
      for (int reg = 0; reg < 4; ++reg) {
        const int grow = m0 + w * 16 + q * 4 + reg;
        const int gcol = n0 + nt * 16 + r;
        float v = acc[nt][reg] + bias[gcol];
        if constexpr (EPI == 1) v = (v > 0.f) ? v : 0.f;
        Cout[(size_t)grow * NDIM + gcol] = f2bf(v);
      }
    }
  }
}

__global__ __launch_bounds__(256) void step_k(ushort* __restrict__ a1,
                                              const void* __restrict__ init,
                                              const void* __restrict__ W1,
                                              const int* __restrict__ tpos,
                                              float* __restrict__ rowsum,
                                              const float* __restrict__ tgt,
                                              float* __restrict__ total,
                                              const uint32_t* __restrict__ flag,
                                              int t) {
  const int m = blockIdx.x;
  const int k = threadIdx.x * 4;
  const bool isbf = (*flag != 0);
  const int tp = tpos[t * BATCH + m];
  const float b0 = isbf ? bf2f(((const ushort*)init)[(size_t)m * NDIM + tp])
                        : ((const float*)init)[(size_t)m * NDIM + tp];
  int cnt = 0;
  for (int u = 0; u < t; ++u) cnt += (tpos[u * BATCH + m] == tp) ? 1 : 0;
  const float bit = (cnt & 1) ? (1.f - b0) : b0;
  const float s = 1.f - 2.f * bit;
  float wx, wy, wz, ww;
  if (isbf) {
    const ushort4 wv = *(const ushort4*)((const ushort*)W1 + (size_t)tp * HID + k);
    wx = bf2f(wv.x); wy = bf2f(wv.y); wz = bf2f(wv.z); ww = bf2f(wv.w);
  } else {
    const float4 wv = *(const float4*)((const float*)W1 + (size_t)tp * HID + k);
    wx = wv.x; wy = wv.y; wz = wv.z; ww = wv.w;
  }
  ushort4 a = *(const ushort4*)(a1 + (size_t)m * HID + k);
  a.x = f2bf(bf2f(a.x) + s * wx);
  a.y = f2bf(bf2f(a.y) + s * wy);
  a.z = f2bf(bf2f(a.z) + s * wz);
  a.w = f2bf(bf2f(a.w) + s * ww);
  *(ushort4*)(a1 + (size_t)m * HID + k) = a;
  if (threadIdx.x == 0) {
    total[m] += tgt[m] - logf(rowsum[m]);
    rowsum[m] = 0.f;
  }
}

__global__ __launch_bounds__(256) void finalize_k(const float* __restrict__ total,
                                                  float* __restrict__ out_total) {
  const int m = blockIdx.x * 256 + threadIdx.x;
  out_total[m] = total[m];
}

// ======================= shared output kernels (fp32) ========================
__global__ __launch_bounds__(256) void out_final_k(const void* __restrict__ init,
                                                   const int* __restrict__ tpos,
                                                   float* __restrict__ out,
                                                   const uint32_t* __restrict__ flag) {
  const int m = blockIdx.x;
  const int k = threadIdx.x * 4;
  const bool isbf = (*flag != 0);
  float v[4];
  if (isbf) {
    const ushort4 iv = *(const ushort4*)((const ushort*)init + (size_t)m * NDIM + k);
    v[0] = bf2f(iv.x); v[1] = bf2f(iv.y); v[2] = bf2f(iv.z); v[3] = bf2f(iv.w);
  } else {
    const float4 iv = *(const float4*)((const float*)init + (size_t)m * NDIM + k);
    v[0] = iv.x; v[1] = iv.y; v[2] = iv.z; v[3] = iv.w;
  }
  for (int t = 0; t < TSTEPS; ++t) {
    const int tp = tpos[t * BATCH + m];
    if ((tp >> 2) == (int)threadIdx.x) v[tp & 3] = 1.f - v[tp & 3];
  }
  float4 o; o.x = v[0]; o.y = v[1]; o.z = v[2]; o.w = v[3];
  *(float4*)(out + OUT_FINAL + (size_t)m * NDIM + k) = o;
}

__global__ __launch_bounds__(256) void out_vinit_k(const void* __restrict__ init,
                                                   float* __restrict__ out,
                                                   const uint32_t* __restrict__ flag) {
  const int i = (blockIdx.x * 256 + threadIdx.x) * 4;
  float4 o;
  if (*flag) {
    const ushort4 iv = *(const ushort4*)((const ushort*)init + i);
    o.x = bf2f(iv.x); o.y = bf2f(iv.y); o.z = bf2f(iv.z); o.w = bf2f(iv.w);
  } else {
    o = *(const float4*)((const float*)init + i);
  }
  *(float4*)(out + OUT_VINIT + i) = o;
}

__global__ __launch_bounds__(256) void out_delta_k(const int* __restrict__ tpos,
                                                   float* __restrict__ out) {
  const int i = blockIdx.x * 256 + threadIdx.x;
  out[OUT_DELTA + i] = (float)tpos[i];
}

extern "C" void kernel_launch(void* const* d_in, const int* in_sizes, int n_in,
                              void* d_out, int out_size, void* d_ws, size_t ws_size,
                              hipStream_t stream) {
  const void* init = d_in[0];
  const int* tpos  = (const int*)d_in[1];
  const void* W1 = d_in[2];
  const void* b1 = d_in[3];
  const void* W2 = d_in[4];
  const void* b2 = d_in[5];
  const void* W3 = d_in[6];
  const void* b3 = d_in[7];
  float* out = (float*)d_out;
  char* ws = (char*)d_ws;

  const size_t MB = 1024ull * 1024ull;
  int CH = TSTEPS;
  while (CH > 1 && (size_t)WF_H1 + (size_t)CH * 8 * MB > ws_size) CH >>= 1;
  const bool fast = (ws_size >= (size_t)WF_H1 + 8 * MB);

  if (fast) {
    ushort*   WT1    = (ushort*)(ws + WF_WT1);
    ushort*   WT2    = (ushort*)(ws + WF_WT2);
    ushort*   WT3    = (ushort*)(ws + WF_WT3);
    float*    a1f    = (float*)(ws + WF_A1);
    float*    biases = (float*)(ws + WF_BIAS);
    uint8_t*  signs  = (uint8_t*)(ws + WF_SIGNS);
    float*    rowsum = (float*)(ws + WF_ROWSUM);
    float*    tgt    = (float*)(ws + WF_TGT);
    uint32_t* flag   = (uint32_t*)(ws + WF_FLAG);
    ushort*   h1     = (ushort*)(ws + WF_H1);
    ushort*   h2     = (ushort*)(ws + WF_H1 + (size_t)CH * 4 * MB);

    flag_k<<<1, 256, 0, stream>>>(init, flag);
    canon_b_k<<<3, 256, 0, stream>>>(b1, b2, b3, biases, flag);
    canon_w_k<<<dim3(32, 32), dim3(32, 8), 0, stream>>>(W1, WT1, flag);
    canon_w_k<<<dim3(32, 32), dim3(32, 8), 0, stream>>>(W2, WT2, flag);
    canon_w_k<<<dim3(32, 32), dim3(32, 8), 0, stream>>>(W3, WT3, flag);
    sign_k<<<BATCH, 256, 0, stream>>>(init, tpos, signs, flag);
    zero_k<<<512, 256, 0, stream>>>(rowsum);   // rowsum|tgt contiguous 131072 f32

    // a1 = init @ W1 + b1  (fp32 out)
    gemm_bt<1, 0><<<dim3(8, 16), 256, 0, stream>>>(init, WT1, biases + 0, a1f,
                                                   nullptr, nullptr, nullptr, flag, 0);

    for (int t0 = 0; t0 < TSTEPS; t0 += CH) {
      build_h1<<<BATCH, 256, 0, stream>>>(a1f, W1, signs, tpos, h1, flag, t0, CH);
      // h2 = relu(h1 @ W2 + b2)   (M = CH*2048)
      gemm_bt<0, 1><<<dim3(8, CH * 16), 256, 0, stream>>>(h1, WT2, biases + 1024, h2,
                                                          nullptr, nullptr, nullptr, flag, 0);
      // logits = h2 @ W3 + b3 -> softmax partials
      gemm_bt<0, 2><<<dim3(8, CH * 16), 256, 0, stream>>>(h2, WT3, biases + 2048, nullptr,
                                                          tpos, rowsum, tgt, flag, t0 * BATCH);
    }
    fin_total_k<<<8, 256, 0, stream>>>(tgt, rowsum, out + OUT_TOTAL);
    out_final_k<<<BATCH, 256, 0, stream>>>(init, tpos, out, flag);
    out_vinit_k<<<2048, 256, 0, stream>>>(init, out, flag);
    out_delta_k<<<256, 256, 0, stream>>>(tpos, out);
  } else {
    // -------- fallback: R8 verified d_out-resident path --------
    ushort*   a1     = (ushort*)(out + OUT_FINAL);
    ushort*   h2     = (ushort*)(out + OUT_VINIT);
    char*     sc     = (char*)(out + OUT_DELTA);
    float*    rowsum = (float*)(sc + SC_ROWSUM);
    float*    tgt    = (float*)(sc + SC_TGT);
    float*    total  = (float*)(sc + SC_TOTAL);
    float*    biases = (float*)(sc + SC_BIAS);
    uint32_t* flag   = (uint32_t*)(sc + SC_FLAG);

    flag_k<<<1, 256, 0, stream>>>(init, flag);
    zero_k<<<24, 256, 0, stream>>>(rowsum);
    canon_b_k<<<3, 256, 0, stream>>>(b1, b2, b3, biases, flag);
    gemm_t<0, 0><<<dim3(16, 32), 256, 0, stream>>>(init, W1, biases + 0, a1,
                                                   nullptr, nullptr, nullptr, flag, 0);
    for (int t = 0; t < TSTEPS; ++t) {
      gemm_t<1, 1><<<dim3(16, 32), 256, 0, stream>>>(a1, W2, biases + 1024, h2,
                                                     nullptr, nullptr, nullptr, flag, 0);
      gemm_t<2, 2><<<dim3(16, 32), 256, 0, stream>>>(h2, W3, biases + 2048, nullptr,
                                                     tpos, rowsum, tgt, flag, t);
      step_k<<<BATCH, 256, 0, stream>>>(a1, init, W1, tpos, rowsum, tgt, total, flag, t);
    }
    finalize_k<<<8, 256, 0, stream>>>(total, out + OUT_TOTAL);
    out_final_k<<<BATCH, 256, 0, stream>>>(init, tpos, out, flag);
    out_vinit_k<<<2048, 256, 0, stream>>>(init, out, flag);
    out_delta_k<<<256, 256, 0, stream>>>(tpos, out);
  }
}

// Round 11
// 592.670 us; speedup vs baseline: 4.5188x; 1.0229x over previous
//
#include <hip/hip_runtime.h>
#include <stdint.h>

#define BATCH 2048
#define NDIM  1024
#define HID   1024
#define TSTEPS 32

// out layout (FP32 elems): final[2048*1024] | delta[32*2048] | total[2048] | vinit[2048*1024]
#define OUT_FINAL 0
#define OUT_DELTA 2097152
#define OUT_TOTAL 2162688
#define OUT_VINIT 2164736

// ---- fallback-path scratch inside the delta region (bytes from out+OUT_DELTA)
#define SC_ROWSUM 0
#define SC_TGT    8192
#define SC_TOTAL  16384
#define SC_BIAS   24576
#define SC_FLAG   36864

// ---- fast-path d_ws layout (bytes) ----
#define WF_WT1    0u           // 2 MB  W1^T bf16 [n][k]
#define WF_WT2    2097152u     // 2 MB
#define WF_WT3    4194304u     // 2 MB
#define WF_A1     6291456u     // 8 MB  fp32 a1 carry
#define WF_BIAS   14680064u    // 12 KB
#define WF_SIGNS  14692352u    // 64 KB
#define WF_ROWSUM 14757888u    // 256 KB
#define WF_TGT    15020032u    // 256 KB
#define WF_FLAG   15282176u    // 4 B
#define WF_H1     15286272u    // CH*4 MB bf16; h2 follows (CH*4 MB)

__device__ __forceinline__ float bf2f(ushort u) {
  union { uint32_t u; float f; } v; v.u = ((uint32_t)u) << 16; return v.f;
}
__device__ __forceinline__ ushort f2bf(float f) {
  union { float f; uint32_t u; } v; v.f = f;
  uint32_t u = v.u;
  u += 0x7fffu + ((u >> 16) & 1u);   // RNE
  return (ushort)(u >> 16);
}

typedef __attribute__((ext_vector_type(8))) short bf16x8;
typedef __attribute__((ext_vector_type(8))) unsigned short u16x8;
typedef __attribute__((ext_vector_type(4))) float f32x4;

__device__ __forceinline__ void gload_lds16(const void* g, void* l) {
  __builtin_amdgcn_global_load_lds((const __attribute__((address_space(1))) void*)g,
                                   (__attribute__((address_space(3))) void*)l, 16, 0, 0);
}

// ---- dtype flag ------------------------------------------------------------
__global__ __launch_bounds__(256) void flag_k(const void* __restrict__ init,
                                              uint32_t* __restrict__ flag) {
  const ushort* p = (const ushort*)init;
  __shared__ uint32_t acc[256];
  uint32_t a = 0;
  for (int i = threadIdx.x; i < 32768; i += 256) a |= p[2 * i];
  acc[threadIdx.x] = a;
  __syncthreads();
  for (int s = 128; s > 0; s >>= 1) {
    if (threadIdx.x < s) acc[threadIdx.x] |= acc[threadIdx.x + s];
    __syncthreads();
  }
  if (threadIdx.x == 0) *flag = (acc[0] != 0) ? 1u : 0u;
}

__global__ __launch_bounds__(256) void zero_k(float* __restrict__ p) {
  p[blockIdx.x * 256 + threadIdx.x] = 0.f;
}

// ---- canonicalize biases -> fp32 -------------------------------------------
__global__ __launch_bounds__(256) void canon_b_k(const void* b1, const void* b2,
                                                 const void* b3,
                                                 float* __restrict__ dst,
                                                 const uint32_t* __restrict__ flag) {
  const void* src = (blockIdx.x == 0) ? b1 : (blockIdx.x == 1) ? b2 : b3;
  float* d = dst + blockIdx.x * 1024;
  const bool isbf = (*flag != 0);
  for (int i = threadIdx.x; i < 1024; i += 256)
    d[i] = isbf ? bf2f(((const ushort*)src)[i]) : ((const float*)src)[i];
}

// ---- canonicalize + transpose all 3 weights (grid.z selects) ---------------
__global__ __launch_bounds__(256) void canon_w3_k(const void* __restrict__ S1,
                                                  const void* __restrict__ S2,
                                                  const void* __restrict__ S3,
                                                  ushort* __restrict__ D,
                                                  const uint32_t* __restrict__ flag) {
  __shared__ ushort tile[32][33];
  const void* S = (blockIdx.z == 0) ? S1 : (blockIdx.z == 1) ? S2 : S3;
  ushort* Dz = D + (size_t)blockIdx.z * 1024 * 1024;
  const int bx = blockIdx.x * 32, by = blockIdx.y * 32;
  const int tx = threadIdx.x, ty = threadIdx.y;  // (32,8)
  const bool isbf = (*flag != 0);
  #pragma unroll
  for (int i = 0; i < 32; i += 8) {
    const size_t idx = (size_t)(by + ty + i) * 1024 + bx + tx;
    tile[ty + i][tx] = isbf ? ((const ushort*)S)[idx] : f2bf(((const float*)S)[idx]);
  }
  __syncthreads();
  #pragma unroll
  for (int i = 0; i < 32; i += 8)
    Dz[(size_t)(bx + ty + i) * 1024 + by + tx] = tile[tx][ty + i];
}

// ---- bit trajectory --------------------------------------------------------
__global__ __launch_bounds__(256) void sign_k(const void* __restrict__ init,
                                              const int* __restrict__ tpos,
                                              uint8_t* __restrict__ signs,
                                              const uint32_t* __restrict__ flag) {
  const int m = blockIdx.x, tid = threadIdx.x;
  const bool isbf = (*flag != 0);
  __shared__ float bits[NDIM];
  #pragma unroll
  for (int i = 0; i < 4; ++i) {
    const int k = tid + i * 256;
    bits[k] = isbf ? bf2f(((const ushort*)init)[(size_t)m * NDIM + k])
                   : ((const float*)init)[(size_t)m * NDIM + k];
  }
  __syncthreads();
  if (tid == 0) {
    for (int t = 0; t < TSTEPS; ++t) {
      const int tp = tpos[t * BATCH + m];
      const float b = bits[tp];
      signs[t * BATCH + m] = (uint8_t)(b != 0.f);
      bits[tp] = 1.f - b;
    }
  }
}

// ============ FAST PATH: 128x128 GEMM, BK=64, XOR-swizzled LDS ==============
// LDS layout: tile row = 64 ushorts (128 B) = 8 chunks of 16 B.
// physical_chunk = logical_chunk ^ (row & 7) — applied at staging source addr
// and at fragment read. Keeps global_load_lds dest contiguous (lane*16) while
// making ds_read_b128 2-way-per-bank (free).
// XCD swizzle: requires gridDim.y % 8 == 0 (here 16 or 256).
template <int ASTAGE, int EPI>
__global__ __launch_bounds__(256) void gemm_bt(const void* __restrict__ A,
                                               const ushort* __restrict__ Bt,
                                               const float* __restrict__ bias,
                                               void* __restrict__ Cout,
                                               const int* __restrict__ tpos,
                                               float* __restrict__ rowsum,
                                               float* __restrict__ tgt,
                                               const uint32_t* __restrict__ flag,
                                               int rowbase) {
  constexpr int BM = 128, BN = 128, BK = 64, K = 1024;
  __shared__ ushort Asm[BM * BK];   // 16 KB
  __shared__ ushort Bsm[BN * BK];   // 16 KB
  const int tid = threadIdx.x;
  const int wave = tid >> 6, lane = tid & 63;
  const int q = lane >> 4, r = lane & 15;

  // ---- XCD-aware (mb, nb) swizzle ----
  const int lid = blockIdx.y * gridDim.x + blockIdx.x;
  const int xcd = lid & 7;
  const int sl  = lid >> 3;
  const int mb  = xcd + 8 * (sl >> 3);
  const int nb  = sl & 7;
  const int n0 = nb * BN;
  const int m0 = mb * BM;
  const int wm = (wave & 1) * 64, wn = (wave >> 1) * 64;

  f32x4 acc[4][4];
  #pragma unroll
  for (int i = 0; i < 4; ++i)
    #pragma unroll
    for (int j = 0; j < 4; ++j)
      #pragma unroll
      for (int e = 0; e < 4; ++e) acc[i][j][e] = 0.f;

  // staging: 4 instrs per matrix; instr j covers LDS bytes j*4096 + tid*16
  int srow[4], ssrc[4], sdst[4];
  #pragma unroll
  for (int j = 0; j < 4; ++j) {
    const int f = j * 4096 + tid * 16;
    const int rw = f >> 7;              // row (128 B per row)
    const int c  = (f & 127) >> 4;      // logical chunk at this LDS slot
    srow[j] = rw;
    ssrc[j] = (c ^ (rw & 7)) * 8;       // swizzled source ushort offset
    sdst[j] = f;
  }
  const bool isbf = (ASTAGE == 1) ? (*flag != 0) : true;

  for (int k0 = 0; k0 < K; k0 += BK) {
    if constexpr (ASTAGE == 0) {
      #pragma unroll
      for (int j = 0; j < 4; ++j)
        gload_lds16((const char*)A + ((size_t)(m0 + srow[j]) * K + k0 + ssrc[j]) * 2,
                    (char*)Asm + sdst[j]);
    } else {
      u16x8 avv[4];
      #pragma unroll
      for (int j = 0; j < 4; ++j) {
        if (isbf) {
          avv[j] = *(const u16x8*)((const ushort*)A + (size_t)(m0 + srow[j]) * K + k0 + ssrc[j]);
        } else {
          const float* fp = (const float*)A + (size_t)(m0 + srow[j]) * K + k0 + ssrc[j];
          const float4 fa = *(const float4*)fp, fb = *(const float4*)(fp + 4);
          avv[j][0] = f2bf(fa.x); avv[j][1] = f2bf(fa.y); avv[j][2] = f2bf(fa.z); avv[j][3] = f2bf(fa.w);
          avv[j][4] = f2bf(fb.x); avv[j][5] = f2bf(fb.y); avv[j][6] = f2bf(fb.z); avv[j][7] = f2bf(fb.w);
        }
      }
      #pragma unroll
      for (int j = 0; j < 4; ++j) *(u16x8*)((char*)Asm + sdst[j]) = avv[j];
    }
    #pragma unroll
    for (int j = 0; j < 4; ++j)
      gload_lds16((const char*)Bt + ((size_t)(n0 + srow[j]) * K + k0 + ssrc[j]) * 2,
                  (char*)Bsm + sdst[j]);
    __syncthreads();   // tiles complete & visible
    #pragma unroll
    for (int s = 0; s < 2; ++s) {     // two K=32 sub-steps of the BK=64 tile
      bf16x8 af[4], bfr[4];
      #pragma unroll
      for (int t = 0; t < 4; ++t) {
        const int ra = wm + t * 16 + r;
        af[t]  = *(const bf16x8*)(Asm + ra * BK + (((s * 4 + q) ^ (ra & 7)) * 8));
        const int rb = wn + t * 16 + r;
        bfr[t] = *(const bf16x8*)(Bsm + rb * BK + (((s * 4 + q) ^ (rb & 7)) * 8));
      }
      #pragma unroll
      for (int mt = 0; mt < 4; ++mt)
        #pragma unroll
        for (int nt = 0; nt < 4; ++nt)
          acc[mt][nt] = __builtin_amdgcn_mfma_f32_16x16x32_bf16(af[mt], bfr[nt], acc[mt][nt], 0, 0, 0);
    }
    __syncthreads();   // all reads done before next staging overwrites
  }

  #pragma unroll
  for (int mt = 0; mt < 4; ++mt) {
    #pragma unroll
    for (int reg = 0; reg < 4; ++reg) {
      const int grow = m0 + wm + mt * 16 + q * 4 + reg;
      if constexpr (EPI == 2) {
        const int growg = rowbase + grow;
        const int tp = tpos[growg];
        float s2 = 0.f;
        #pragma unroll
        for (int nt = 0; nt < 4; ++nt) {
          const int gcol = n0 + wn + nt * 16 + r;
          const float v = acc[mt][nt][reg] + bias[gcol];
          if (gcol == tp) tgt[growg] = v;
          s2 += __expf(v);
        }
        s2 += __shfl_xor(s2, 1);
        s2 += __shfl_xor(s2, 2);
        s2 += __shfl_xor(s2, 4);
        s2 += __shfl_xor(s2, 8);
        if (r == 0) atomicAdd(&rowsum[growg], s2);
      } else {
        #pragma unroll
        for (int nt = 0; nt < 4; ++nt) {
          const int gcol = n0 + wn + nt * 16 + r;
          const float v = acc[mt][nt][reg] + bias[gcol];
          if constexpr (EPI == 0) {
            ((float*)Cout)[(size_t)grow * NDIM + gcol] = v;
          } else {
            ((ushort*)Cout)[(size_t)grow * NDIM + gcol] = f2bf(v > 0.f ? v : 0.f);
          }
        }
      }
    }
  }
}

// ---- h1 chunk: fp32 a1 recurrence + relu -> bf16 ---------------------------
__global__ __launch_bounds__(256) void build_h1(float* __restrict__ a1,
                                                const void* __restrict__ W1,
                                                const uint8_t* __restrict__ signs,
                                                const int* __restrict__ tpos,
                                                ushort* __restrict__ h1,
                                                const uint32_t* __restrict__ flag,
                                                int t0, int nsteps) {
  const int m = blockIdx.x;
  const int k = threadIdx.x * 4;
  const bool isbf = (*flag != 0);
  float4 a = *(const float4*)(a1 + (size_t)m * HID + k);
  for (int t = 0; t < nsteps; ++t) {
    ushort4 h;
    h.x = f2bf(a.x > 0.f ? a.x : 0.f);
    h.y = f2bf(a.y > 0.f ? a.y : 0.f);
    h.z = f2bf(a.z > 0.f ? a.z : 0.f);
    h.w = f2bf(a.w > 0.f ? a.w : 0.f);
    *(ushort4*)(h1 + ((size_t)(t * BATCH + m)) * HID + k) = h;
    const int tg = t0 + t;
    const int tp = tpos[tg * BATCH + m];
    const float s = 1.f - 2.f * (float)signs[tg * BATCH + m];
    float wx, wy, wz, ww;
    if (isbf) {
      const ushort4 wv = *(const ushort4*)((const ushort*)W1 + (size_t)tp * HID + k);
      wx = bf2f(wv.x); wy = bf2f(wv.y); wz = bf2f(wv.z); ww = bf2f(wv.w);
    } else {
      const float4 wv = *(const float4*)((const float*)W1 + (size_t)tp * HID + k);
      wx = wv.x; wy = wv.y; wz = wv.z; ww = wv.w;
    }
    a.x += s * wx; a.y += s * wy; a.z += s * wz; a.w += s * ww;
  }
  *(float4*)(a1 + (size_t)m * HID + k) = a;
}

// ---- total_log -> d_out ----------------------------------------------------
__global__ __launch_bounds__(256) void fin_total_k(const float* __restrict__ tgt,
                                                   const float* __restrict__ rowsum,
                                                   float* __restrict__ out_total) {
  const int m = blockIdx.x * 256 + threadIdx.x;
  float acc = 0.f;
  for (int t = 0; t < TSTEPS; ++t) {
    const int rr = t * BATCH + m;
    acc += tgt[rr] - logf(rowsum[rr]);
  }
  out_total[m] = acc;
}

// ======================= FALLBACK PATH (R8, verified green) ==================
template <int ASRC, int EPI>
__global__ __launch_bounds__(256) void gemm_t(const void* __restrict__ A,
                                              const void* __restrict__ W,
                                              const float* __restrict__ bias,
                                              ushort* __restrict__ Cout,
                                              const int* __restrict__ tpos,
                                              float* __restrict__ rowsum,
                                              float* __restrict__ tgt,
                                              const uint32_t* __restrict__ flag,
                                              int tstep) {
  constexpr int BM = 64, BN = 64, BK = 32, BKP = 40, K = 1024;
  __shared__ ushort Asm[BM * BKP];
  __shared__ ushort Bsm[BN * BKP];
  const int tid = threadIdx.x;
  const int w = tid >> 6, lane = tid & 63;
  const int q = lane >> 4, r = lane & 15;
  const int n0 = blockIdx.x * BN;
  const int m0 = blockIdx.y * BM;
  const bool isbf = (*flag != 0);
  const int srow = tid >> 2, scol = (tid & 3) * 8;
  const int kk = tid >> 3, ng = (tid & 7) * 8;

  f32x4 acc[4];
  #pragma unroll
  for (int nt = 0; nt < 4; ++nt)
    #pragma unroll
    for (int e = 0; e < 4; ++e) acc[nt][e] = 0.f;

  for (int k0 = 0; k0 < K; k0 += BK) {
    u16x8 av;
    if constexpr (ASRC == 0) {
      if (isbf) {
        av = *(const u16x8*)((const ushort*)A + (size_t)(m0 + srow) * K + k0 + scol);
      } else {
        const float* fp = (const float*)A + (size_t)(m0 + srow) * K + k0 + scol;
        const float4 fa = *(const float4*)fp, fb = *(const float4*)(fp + 4);
        av[0] = f2bf(fa.x); av[1] = f2bf(fa.y); av[2] = f2bf(fa.z); av[3] = f2bf(fa.w);
        av[4] = f2bf(fb.x); av[5] = f2bf(fb.y); av[6] = f2bf(fb.z); av[7] = f2bf(fb.w);
      }
    } else {
      av = *(const u16x8*)((const ushort*)A + (size_t)(m0 + srow) * K + k0 + scol);
      if constexpr (ASRC == 1) {
        #pragma unroll
        for (int e = 0; e < 8; ++e) av[e] = (av[e] & 0x8000u) ? (unsigned short)0 : av[e];
      }
    }
    ushort bw[8];
    if (isbf) {
      const u16x8 wv = *(const u16x8*)((const ushort*)W + (size_t)(k0 + kk) * NDIM + n0 + ng);
      #pragma unroll
      for (int j = 0; j < 8; ++j) bw[j] = wv[j];
    } else {
      const float* fp = (const float*)W + (size_t)(k0 + kk) * NDIM + n0 + ng;
      const float4 fa = *(const float4*)fp, fb = *(const float4*)(fp + 4);
      bw[0] = f2bf(fa.x); bw[1] = f2bf(fa.y); bw[2] = f2bf(fa.z); bw[3] = f2bf(fa.w);
      bw[4] = f2bf(fb.x); bw[5] = f2bf(fb.y); bw[6] = f2bf(fb.z); bw[7] = f2bf(fb.w);
    }
    __syncthreads();
    *(u16x8*)(Asm + srow * BKP + scol) = av;
    #pragma unroll
    for (int j = 0; j < 8; ++j) Bsm[(ng + j) * BKP + kk] = bw[j];
    __syncthreads();
    const bf16x8 af = *(const bf16x8*)(Asm + (w * 16 + r) * BKP + q * 8);
    #pragma unroll
    for (int nt = 0; nt < 4; ++nt) {
      const bf16x8 bfr = *(const bf16x8*)(Bsm + (nt * 16 + r) * BKP + q * 8);
      acc[nt] = __builtin_amdgcn_mfma_f32_16x16x32_bf16(af, bfr, acc[nt], 0, 0, 0);
    }
  }

  if constexpr (EPI == 2) {
    #pragma unroll
    for (int reg = 0; reg < 4; ++reg) {
      const int grow = m0 + w * 16 + q * 4 + reg;
      const int tp = tpos[tstep * BATCH + grow];
      float s = 0.f;
      #pragma unroll
      for (int nt = 0; nt < 4; ++nt) {
        const int gcol = n0 + nt * 16 + r;
        const float v = acc[nt][reg] + bias[gcol];
        if (gcol == tp) tgt[grow] = v;
        s += __expf(v);
      }
      s += __shfl_xor(s, 1);
      s += __shfl_xor(s, 2);
      s += __shfl_xor(s, 4);
      s += __shfl_xor(s, 8);
      if (r == 0) atomicAdd(&rowsum[grow], s);
    }
  } else {
    #pragma unroll
    for (int nt = 0; nt < 4; ++nt) {
      #pragma unroll
      for (int reg = 0; reg < 4; ++reg) {
        const int grow = m0 + w * 16 + q * 4 + reg;
        const int gcol = n0 + nt * 16 + r;
        float v = acc[nt][reg] + bias[gcol];
        if constexpr (EPI == 1) v = (v > 0.f) ? v : 0.f;
        Cout[(size_t)grow * NDIM + gcol] = f2bf(v);
      }
    }
  }
}

__global__ __launch_bounds__(256) void step_k(ushort* __restrict__ a1,
                                              const void* __restrict__ init,
                                              const void* __restrict__ W1,
                                              const int* __restrict__ tpos,
                                              float* __restrict__ rowsum,
                                              const float* __restrict__ tgt,
                                              float* __restrict__ total,
                                              const uint32_t* __restrict__ flag,
                                              int t) {
  const int m = blockIdx.x;
  const int k = threadIdx.x * 4;
  const bool isbf = (*flag != 0);
  const int tp = tpos[t * BATCH + m];
  const float b0 = isbf ? bf2f(((const ushort*)init)[(size_t)m * NDIM + tp])
                        : ((const float*)init)[(size_t)m * NDIM + tp];
  int cnt = 0;
  for (int u = 0; u < t; ++u) cnt += (tpos[u * BATCH + m] == tp) ? 1 : 0;
  const float bit = (cnt & 1) ? (1.f - b0) : b0;
  const float s = 1.f - 2.f * bit;
  float wx, wy, wz, ww;
  if (isbf) {
    const ushort4 wv = *(const ushort4*)((const ushort*)W1 + (size_t)tp * HID + k);
    wx = bf2f(wv.x); wy = bf2f(wv.y); wz = bf2f(wv.z); ww = bf2f(wv.w);
  } else {
    const float4 wv = *(const float4*)((const float*)W1 + (size_t)tp * HID + k);
    wx = wv.x; wy = wv.y; wz = wv.z; ww = wv.w;
  }
  ushort4 a = *(const ushort4*)(a1 + (size_t)m * HID + k);
  a.x = f2bf(bf2f(a.x) + s * wx);
  a.y = f2bf(bf2f(a.y) + s * wy);
  a.z = f2bf(bf2f(a.z) + s * wz);
  a.w = f2bf(bf2f(a.w) + s * ww);
  *(ushort4*)(a1 + (size_t)m * HID + k) = a;
  if (threadIdx.x == 0) {
    total[m] += tgt[m] - logf(rowsum[m]);
    rowsum[m] = 0.f;
  }
}

__global__ __launch_bounds__(256) void finalize_k(const float* __restrict__ total,
                                                  float* __restrict__ out_total) {
  const int m = blockIdx.x * 256 + threadIdx.x;
  out_total[m] = total[m];
}

// ======================= shared output kernels (fp32) ========================
__global__ __launch_bounds__(256) void out_final_k(const void* __restrict__ init,
                                                   const int* __restrict__ tpos,
                                                   float* __restrict__ out,
                                                   const uint32_t* __restrict__ flag) {
  const int m = blockIdx.x;
  const int k = threadIdx.x * 4;
  const bool isbf = (*flag != 0);
  float v[4];
  if (isbf) {
    const ushort4 iv = *(const ushort4*)((const ushort*)init + (size_t)m * NDIM + k);
    v[0] = bf2f(iv.x); v[1] = bf2f(iv.y); v[2] = bf2f(iv.z); v[3] = bf2f(iv.w);
  } else {
    const float4 iv = *(const float4*)((const float*)init + (size_t)m * NDIM + k);
    v[0] = iv.x; v[1] = iv.y; v[2] = iv.z; v[3] = iv.w;
  }
  for (int t = 0; t < TSTEPS; ++t) {
    const int tp = tpos[t * BATCH + m];
    if ((tp >> 2) == (int)threadIdx.x) v[tp & 3] = 1.f - v[tp & 3];
  }
  float4 o; o.x = v[0]; o.y = v[1]; o.z = v[2]; o.w = v[3];
  *(float4*)(out + OUT_FINAL + (size_t)m * NDIM + k) = o;
}

__global__ __launch_bounds__(256) void out_vinit_k(const void* __restrict__ init,
                                                   float* __restrict__ out,
                                                   const uint32_t* __restrict__ flag) {
  const int i = (blockIdx.x * 256 + threadIdx.x) * 4;
  float4 o;
  if (*flag) {
    const ushort4 iv = *(const ushort4*)((const ushort*)init + i);
    o.x = bf2f(iv.x); o.y = bf2f(iv.y); o.z = bf2f(iv.z); o.w = bf2f(iv.w);
  } else {
    o = *(const float4*)((const float*)init + i);
  }
  *(float4*)(out + OUT_VINIT + i) = o;
}

__global__ __launch_bounds__(256) void out_delta_k(const int* __restrict__ tpos,
                                                   float* __restrict__ out) {
  const int i = blockIdx.x * 256 + threadIdx.x;
  out[OUT_DELTA + i] = (float)tpos[i];
}

extern "C" void kernel_launch(void* const* d_in, const int* in_sizes, int n_in,
                              void* d_out, int out_size, void* d_ws, size_t ws_size,
                              hipStream_t stream) {
  const void* init = d_in[0];
  const int* tpos  = (const int*)d_in[1];
  const void* W1 = d_in[2];
  const void* b1 = d_in[3];
  const void* W2 = d_in[4];
  const void* b2 = d_in[5];
  const void* W3 = d_in[6];
  const void* b3 = d_in[7];
  float* out = (float*)d_out;
  char* ws = (char*)d_ws;

  const size_t MB = 1024ull * 1024ull;
  int CH = TSTEPS;
  while (CH > 1 && (size_t)WF_H1 + (size_t)CH * 8 * MB > ws_size) CH >>= 1;
  const bool fast = (ws_size >= (size_t)WF_H1 + 8 * MB);

  if (fast) {
    ushort*   WT1    = (ushort*)(ws + WF_WT1);
    ushort*   WT2    = (ushort*)(ws + WF_WT2);
    ushort*   WT3    = (ushort*)(ws + WF_WT3);
    float*    a1f    = (float*)(ws + WF_A1);
    float*    biases = (float*)(ws + WF_BIAS);
    uint8_t*  signs  = (uint8_t*)(ws + WF_SIGNS);
    float*    rowsum = (float*)(ws + WF_ROWSUM);
    float*    tgt    = (float*)(ws + WF_TGT);
    uint32_t* flag   = (uint32_t*)(ws + WF_FLAG);
    ushort*   h1     = (ushort*)(ws + WF_H1);
    ushort*   h2     = (ushort*)(ws + WF_H1 + (size_t)CH * 4 * MB);

    flag_k<<<1, 256, 0, stream>>>(init, flag);
    canon_b_k<<<3, 256, 0, stream>>>(b1, b2, b3, biases, flag);
    canon_w3_k<<<dim3(32, 32, 3), dim3(32, 8), 0, stream>>>(W1, W2, W3, WT1, flag);
    sign_k<<<BATCH, 256, 0, stream>>>(init, tpos, signs, flag);
    zero_k<<<512, 256, 0, stream>>>(rowsum);   // rowsum|tgt contiguous

    // a1 = init @ W1 + b1  (fp32 out)
    gemm_bt<1, 0><<<dim3(8, 16), 256, 0, stream>>>(init, WT1, biases + 0, a1f,
                                                   nullptr, nullptr, nullptr, flag, 0);

    for (int t0 = 0; t0 < TSTEPS; t0 += CH) {
      build_h1<<<BATCH, 256, 0, stream>>>(a1f, W1, signs, tpos, h1, flag, t0, CH);
      gemm_bt<0, 1><<<dim3(8, CH * 16), 256, 0, stream>>>(h1, WT2, biases + 1024, h2,
                                                          nullptr, nullptr, nullptr, flag, 0);
      gemm_bt<0, 2><<<dim3(8, CH * 16), 256, 0, stream>>>(h2, WT3, biases + 2048, nullptr,
                                                          tpos, rowsum, tgt, flag, t0 * BATCH);
    }
    fin_total_k<<<8, 256, 0, stream>>>(tgt, rowsum, out + OUT_TOTAL);
    out_final_k<<<BATCH, 256, 0, stream>>>(init, tpos, out, flag);
    out_vinit_k<<<2048, 256, 0, stream>>>(init, out, flag);
    out_delta_k<<<256, 256, 0, stream>>>(tpos, out);
  } else {
    // -------- fallback: R8 verified d_out-resident path --------
    ushort*   a1     = (ushort*)(out + OUT_FINAL);
    ushort*   h2     = (ushort*)(out + OUT_VINIT);
    char*     sc     = (char*)(out + OUT_DELTA);
    float*    rowsum = (float*)(sc + SC_ROWSUM);
    float*    tgt    = (float*)(sc + SC_TGT);
    float*    total  = (float*)(sc + SC_TOTAL);
    float*    biases = (float*)(sc + SC_BIAS);
    uint32_t* flag   = (uint32_t*)(sc + SC_FLAG);

    flag_k<<<1, 256, 0, stream>>>(init, flag);
    zero_k<<<24, 256, 0, stream>>>(rowsum);
    canon_b_k<<<3, 256, 0, stream>>>(b1, b2, b3, biases, flag);
    gemm_t<0, 0><<<dim3(16, 32), 256, 0, stream>>>(init, W1, biases + 0, a1,
                                                   nullptr, nullptr, nullptr, flag, 0);
    for (int t = 0; t < TSTEPS; ++t) {
      gemm_t<1, 1><<<dim3(16, 32), 256, 0, stream>>>(a1, W2, biases + 1024, h2,
                                                     nullptr, nullptr, nullptr, flag, 0);
      gemm_t<2, 2><<<dim3(16, 32), 256, 0, stream>>>(h2, W3, biases + 2048, nullptr,
                                                     tpos, rowsum, tgt, flag, t);
      step_k<<<BATCH, 256, 0, stream>>>(a1, init, W1, tpos, rowsum, tgt, total, flag, t);
    }
    finalize_k<<<8, 256, 0, stream>>>(total, out + OUT_TOTAL);
    out_final_k<<<BATCH, 256, 0, stream>>>(init, tpos, out, flag);
    out_vinit_k<<<2048, 256, 0, stream>>>(init, out, flag);
    out_delta_k<<<256, 256, 0, stream>>>(tpos, out);
  }
}

// Round 12
// 592.036 us; speedup vs baseline: 4.5237x; 1.0011x over previous
//
#include <hip/hip_runtime.h>
#include <stdint.h>

#define BATCH 2048
#define NDIM  1024
#define HID   1024
#define TSTEPS 32

// out layout (FP32 elems): final[2048*1024] | delta[32*2048] | total[2048] | vinit[2048*1024]
#define OUT_FINAL 0
#define OUT_DELTA 2097152
#define OUT_TOTAL 2162688
#define OUT_VINIT 2164736

// ---- fallback-path scratch inside the delta region (bytes from out+OUT_DELTA)
#define SC_ROWSUM 0
#define SC_TGT    8192
#define SC_TOTAL  16384
#define SC_BIAS   24576
#define SC_FLAG   36864

// ---- fast-path d_ws layout (bytes) ----
#define WF_WT1    0u           // 2 MB  W1^T bf16 [n][k]
#define WF_WT2    2097152u     // 2 MB
#define WF_WT3    4194304u     // 2 MB
#define WF_A1     6291456u     // 8 MB  fp32 a1 carry
#define WF_BIAS   14680064u    // 12 KB
#define WF_SIGNS  14692352u    // 64 KB
#define WF_ROWSUM 14757888u    // 256 KB
#define WF_TGT    15020032u    // 256 KB
#define WF_FLAG   15282176u    // 4 B
#define WF_H1     15286272u    // CH*4 MB bf16; h2 follows (CH*4 MB)

__device__ __forceinline__ float bf2f(ushort u) {
  union { uint32_t u; float f; } v; v.u = ((uint32_t)u) << 16; return v.f;
}
__device__ __forceinline__ ushort f2bf(float f) {
  union { float f; uint32_t u; } v; v.f = f;
  uint32_t u = v.u;
  u += 0x7fffu + ((u >> 16) & 1u);   // RNE
  return (ushort)(u >> 16);
}

typedef __attribute__((ext_vector_type(8))) short bf16x8;
typedef __attribute__((ext_vector_type(8))) unsigned short u16x8;
typedef __attribute__((ext_vector_type(4))) float f32x4;

// ---- dtype flag ------------------------------------------------------------
__global__ __launch_bounds__(256) void flag_k(const void* __restrict__ init,
                                              uint32_t* __restrict__ flag) {
  const ushort* p = (const ushort*)init;
  __shared__ uint32_t acc[256];
  uint32_t a = 0;
  for (int i = threadIdx.x; i < 32768; i += 256) a |= p[2 * i];
  acc[threadIdx.x] = a;
  __syncthreads();
  for (int s = 128; s > 0; s >>= 1) {
    if (threadIdx.x < s) acc[threadIdx.x] |= acc[threadIdx.x + s];
    __syncthreads();
  }
  if (threadIdx.x == 0) *flag = (acc[0] != 0) ? 1u : 0u;
}

__global__ __launch_bounds__(256) void zero_k(float* __restrict__ p) {
  p[blockIdx.x * 256 + threadIdx.x] = 0.f;
}

// ---- canonicalize biases -> fp32 -------------------------------------------
__global__ __launch_bounds__(256) void canon_b_k(const void* b1, const void* b2,
                                                 const void* b3,
                                                 float* __restrict__ dst,
                                                 const uint32_t* __restrict__ flag) {
  const void* src = (blockIdx.x == 0) ? b1 : (blockIdx.x == 1) ? b2 : b3;
  float* d = dst + blockIdx.x * 1024;
  const bool isbf = (*flag != 0);
  for (int i = threadIdx.x; i < 1024; i += 256)
    d[i] = isbf ? bf2f(((const ushort*)src)[i]) : ((const float*)src)[i];
}

// ---- canonicalize + transpose all 3 weights --------------------------------
__global__ __launch_bounds__(256) void canon_w3_k(const void* __restrict__ S1,
                                                  const void* __restrict__ S2,
                                                  const void* __restrict__ S3,
                                                  ushort* __restrict__ D,
                                                  const uint32_t* __restrict__ flag) {
  __shared__ ushort tile[32][33];
  const void* S = (blockIdx.z == 0) ? S1 : (blockIdx.z == 1) ? S2 : S3;
  ushort* Dz = D + (size_t)blockIdx.z * 1024 * 1024;
  const int bx = blockIdx.x * 32, by = blockIdx.y * 32;
  const int tx = threadIdx.x, ty = threadIdx.y;  // (32,8)
  const bool isbf = (*flag != 0);
  #pragma unroll
  for (int i = 0; i < 32; i += 8) {
    const size_t idx = (size_t)(by + ty + i) * 1024 + bx + tx;
    tile[ty + i][tx] = isbf ? ((const ushort*)S)[idx] : f2bf(((const float*)S)[idx]);
  }
  __syncthreads();
  #pragma unroll
  for (int i = 0; i < 32; i += 8)
    Dz[(size_t)(bx + ty + i) * 1024 + by + tx] = tile[tx][ty + i];
}

// ---- bit trajectory + zero rowsum/tgt --------------------------------------
__global__ __launch_bounds__(256) void sign_k(const void* __restrict__ init,
                                              const int* __restrict__ tpos,
                                              uint8_t* __restrict__ signs,
                                              float* __restrict__ rowsum,
                                              float* __restrict__ tgt,
                                              const uint32_t* __restrict__ flag) {
  const int m = blockIdx.x, tid = threadIdx.x;
  const bool isbf = (*flag != 0);
  __shared__ float bits[NDIM];
  #pragma unroll
  for (int i = 0; i < 4; ++i) {
    const int k = tid + i * 256;
    bits[k] = isbf ? bf2f(((const ushort*)init)[(size_t)m * NDIM + k])
                   : ((const float*)init)[(size_t)m * NDIM + k];
  }
  __syncthreads();
  if (tid == 0) {
    for (int t = 0; t < TSTEPS; ++t) {
      const int tp = tpos[t * BATCH + m];
      const float b = bits[tp];
      signs[t * BATCH + m] = (uint8_t)(b != 0.f);
      bits[tp] = 1.f - b;
    }
  }
  if (tid < 32) rowsum[m * 32 + tid] = 0.f;
  else if (tid < 64) tgt[m * 32 + (tid - 32)] = 0.f;
}

// ====== FAST PATH: 128x128 GEMM, BK=32, VGPR-prefetch pipeline ==============
// Staging: global->VGPR (prefetched one iter ahead) -> ds_write_b128.
// The vmcnt wait for tile k+1 loads lands at NEXT iter's ds_write — i.e. after
// a full MFMA phase — so HBM/L2 latency hides behind compute (unlike
// global_load_lds, whose vmcnt(0) drain before s_barrier exposes it).
// LDS row stride 40 ushorts (80 B): ds_read/write_b128 2-way-per-bank (free).
// XCD swizzle: requires gridDim.y % 8 == 0.
template <int ASTAGE, int EPI>
__global__ __launch_bounds__(256) void gemm_bt(const void* __restrict__ A,
                                               const ushort* __restrict__ Bt,
                                               const float* __restrict__ bias,
                                               void* __restrict__ Cout,
                                               const int* __restrict__ tpos,
                                               float* __restrict__ rowsum,
                                               float* __restrict__ tgt,
                                               const uint32_t* __restrict__ flag,
                                               int rowbase) {
  constexpr int BM = 128, BN = 128, BK = 32, LS = 40, K = 1024;
  __shared__ ushort Asm[BM * LS];   // 10 KB
  __shared__ ushort Bsm[BN * LS];   // 10 KB
  const int tid = threadIdx.x;
  const int wave = tid >> 6, lane = tid & 63;
  const int q = lane >> 4, r = lane & 15;

  // ---- XCD-aware (mb, nb) swizzle ----
  const int lid = blockIdx.y * gridDim.x + blockIdx.x;
  const int xcd = lid & 7;
  const int sl  = lid >> 3;
  const int mb  = xcd + 8 * (sl >> 3);
  const int nb  = sl & 7;
  const int n0 = nb * BN;
  const int m0 = mb * BM;
  const int wm = (wave & 1) * 64, wn = (wave >> 1) * 64;

  f32x4 acc[4][4];
  #pragma unroll
  for (int i = 0; i < 4; ++i)
    #pragma unroll
    for (int j = 0; j < 4; ++j)
      #pragma unroll
      for (int e = 0; e < 4; ++e) acc[i][j][e] = 0.f;

  // staging coords: thread covers rows (tid>>2) and 64+(tid>>2), chunk tid&3
  const int row = tid >> 2, c8 = (tid & 3) * 8;
  const bool isbf = (ASTAGE == 1) ? (*flag != 0) : true;

  u16x8 pa0, pa1, pb0, pb1;
  // ---- prologue: load tile k0=0 into regs ----
  {
    if constexpr (ASTAGE == 1) {
      if (isbf) {
        pa0 = *(const u16x8*)((const ushort*)A + (size_t)(m0 + row) * K + c8);
        pa1 = *(const u16x8*)((const ushort*)A + (size_t)(m0 + 64 + row) * K + c8);
      } else {
        const float* p0 = (const float*)A + (size_t)(m0 + row) * K + c8;
        const float* p1 = (const float*)A + (size_t)(m0 + 64 + row) * K + c8;
        const float4 fa = *(const float4*)p0, fb = *(const float4*)(p0 + 4);
        const float4 fc = *(const float4*)p1, fd = *(const float4*)(p1 + 4);
        pa0[0] = f2bf(fa.x); pa0[1] = f2bf(fa.y); pa0[2] = f2bf(fa.z); pa0[3] = f2bf(fa.w);
        pa0[4] = f2bf(fb.x); pa0[5] = f2bf(fb.y); pa0[6] = f2bf(fb.z); pa0[7] = f2bf(fb.w);
        pa1[0] = f2bf(fc.x); pa1[1] = f2bf(fc.y); pa1[2] = f2bf(fc.z); pa1[3] = f2bf(fc.w);
        pa1[4] = f2bf(fd.x); pa1[5] = f2bf(fd.y); pa1[6] = f2bf(fd.z); pa1[7] = f2bf(fd.w);
      }
    } else {
      pa0 = *(const u16x8*)((const ushort*)A + (size_t)(m0 + row) * K + c8);
      pa1 = *(const u16x8*)((const ushort*)A + (size_t)(m0 + 64 + row) * K + c8);
    }
    pb0 = *(const u16x8*)(Bt + (size_t)(n0 + row) * K + c8);
    pb1 = *(const u16x8*)(Bt + (size_t)(n0 + 64 + row) * K + c8);
  }

  for (int k0 = 0; k0 < K; k0 += BK) {
    __syncthreads();                       // prior-iter LDS reads done
    *(u16x8*)(Asm + row * LS + c8) = pa0;
    *(u16x8*)(Asm + (64 + row) * LS + c8) = pa1;
    *(u16x8*)(Bsm + row * LS + c8) = pb0;
    *(u16x8*)(Bsm + (64 + row) * LS + c8) = pb1;
    // ---- prefetch tile k0+BK (wrapped on last iter: harmless reload) ----
    {
      const int kn = (k0 + BK) & (K - 1);
      if constexpr (ASTAGE == 1) {
        if (isbf) {
          pa0 = *(const u16x8*)((const ushort*)A + (size_t)(m0 + row) * K + kn + c8);
          pa1 = *(const u16x8*)((const ushort*)A + (size_t)(m0 + 64 + row) * K + kn + c8);
        } else {
          const float* p0 = (const float*)A + (size_t)(m0 + row) * K + kn + c8;
          const float* p1 = (const float*)A + (size_t)(m0 + 64 + row) * K + kn + c8;
          const float4 fa = *(const float4*)p0, fb = *(const float4*)(p0 + 4);
          const float4 fc = *(const float4*)p1, fd = *(const float4*)(p1 + 4);
          pa0[0] = f2bf(fa.x); pa0[1] = f2bf(fa.y); pa0[2] = f2bf(fa.z); pa0[3] = f2bf(fa.w);
          pa0[4] = f2bf(fb.x); pa0[5] = f2bf(fb.y); pa0[6] = f2bf(fb.z); pa0[7] = f2bf(fb.w);
          pa1[0] = f2bf(fc.x); pa1[1] = f2bf(fc.y); pa1[2] = f2bf(fc.z); pa1[3] = f2bf(fc.w);
          pa1[4] = f2bf(fd.x); pa1[5] = f2bf(fd.y); pa1[6] = f2bf(fd.z); pa1[7] = f2bf(fd.w);
        }
      } else {
        pa0 = *(const u16x8*)((const ushort*)A + (size_t)(m0 + row) * K + kn + c8);
        pa1 = *(const u16x8*)((const ushort*)A + (size_t)(m0 + 64 + row) * K + kn + c8);
      }
      pb0 = *(const u16x8*)(Bt + (size_t)(n0 + row) * K + kn + c8);
      pb1 = *(const u16x8*)(Bt + (size_t)(n0 + 64 + row) * K + kn + c8);
    }
    __syncthreads();                       // tile visible
    bf16x8 af[4], bfr[4];
    #pragma unroll
    for (int t = 0; t < 4; ++t) {
      af[t]  = *(const bf16x8*)(Asm + (wm + t * 16 + r) * LS + q * 8);
      bfr[t] = *(const bf16x8*)(Bsm + (wn + t * 16 + r) * LS + q * 8);
    }
    #pragma unroll
    for (int mt = 0; mt < 4; ++mt)
      #pragma unroll
      for (int nt = 0; nt < 4; ++nt)
        acc[mt][nt] = __builtin_amdgcn_mfma_f32_16x16x32_bf16(af[mt], bfr[nt], acc[mt][nt], 0, 0, 0);
  }

  #pragma unroll
  for (int mt = 0; mt < 4; ++mt) {
    #pragma unroll
    for (int reg = 0; reg < 4; ++reg) {
      const int grow = m0 + wm + mt * 16 + q * 4 + reg;
      if constexpr (EPI == 2) {
        const int growg = rowbase + grow;
        const int tp = tpos[growg];
        float s2 = 0.f;
        #pragma unroll
        for (int nt = 0; nt < 4; ++nt) {
          const int gcol = n0 + wn + nt * 16 + r;
          const float v = acc[mt][nt][reg] + bias[gcol];
          if (gcol == tp) tgt[growg] = v;
          s2 += __expf(v);
        }
        s2 += __shfl_xor(s2, 1);
        s2 += __shfl_xor(s2, 2);
        s2 += __shfl_xor(s2, 4);
        s2 += __shfl_xor(s2, 8);
        if (r == 0) atomicAdd(&rowsum[growg], s2);
      } else {
        #pragma unroll
        for (int nt = 0; nt < 4; ++nt) {
          const int gcol = n0 + wn + nt * 16 + r;
          const float v = acc[mt][nt][reg] + bias[gcol];
          if constexpr (EPI == 0) {
            ((float*)Cout)[(size_t)grow * NDIM + gcol] = v;
          } else {
            ((ushort*)Cout)[(size_t)grow * NDIM + gcol] = f2bf(v > 0.f ? v : 0.f);
          }
        }
      }
    }
  }
}

// ---- h1 chunk: fp32 a1 recurrence + relu -> bf16 ---------------------------
__global__ __launch_bounds__(256) void build_h1(float* __restrict__ a1,
                                                const void* __restrict__ W1,
                                                const uint8_t* __restrict__ signs,
                                                const int* __restrict__ tpos,
                                                ushort* __restrict__ h1,
                                                const uint32_t* __restrict__ flag,
                                                int t0, int nsteps) {
  const int m = blockIdx.x;
  const int k = threadIdx.x * 4;
  const bool isbf = (*flag != 0);
  float4 a = *(const float4*)(a1 + (size_t)m * HID + k);
  for (int t = 0; t < nsteps; ++t) {
    ushort4 h;
    h.x = f2bf(a.x > 0.f ? a.x : 0.f);
    h.y = f2bf(a.y > 0.f ? a.y : 0.f);
    h.z = f2bf(a.z > 0.f ? a.z : 0.f);
    h.w = f2bf(a.w > 0.f ? a.w : 0.f);
    *(ushort4*)(h1 + ((size_t)(t * BATCH + m)) * HID + k) = h;
    const int tg = t0 + t;
    const int tp = tpos[tg * BATCH + m];
    const float s = 1.f - 2.f * (float)signs[tg * BATCH + m];
    float wx, wy, wz, ww;
    if (isbf) {
      const ushort4 wv = *(const ushort4*)((const ushort*)W1 + (size_t)tp * HID + k);
      wx = bf2f(wv.x); wy = bf2f(wv.y); wz = bf2f(wv.z); ww = bf2f(wv.w);
    } else {
      const float4 wv = *(const float4*)((const float*)W1 + (size_t)tp * HID + k);
      wx = wv.x; wy = wv.y; wz = wv.z; ww = wv.w;
    }
    a.x += s * wx; a.y += s * wy; a.z += s * wz; a.w += s * ww;
  }
  *(float4*)(a1 + (size_t)m * HID + k) = a;
}

// ---- merged outputs: final+vinit (row m), delta, total_log -----------------
// Fast path only: scratch lives in d_ws, so no ordering hazard vs d_out.
__global__ __launch_bounds__(256) void outputs_k(const void* __restrict__ init,
                                                 const int* __restrict__ tpos,
                                                 const float* __restrict__ tgt,
                                                 const float* __restrict__ rowsum,
                                                 float* __restrict__ out,
                                                 const uint32_t* __restrict__ flag) {
  const int m = blockIdx.x;
  const int tid = threadIdx.x;
  const int k = tid * 4;
  const bool isbf = (*flag != 0);
  float v[4];
  if (isbf) {
    const ushort4 iv = *(const ushort4*)((const ushort*)init + (size_t)m * NDIM + k);
    v[0] = bf2f(iv.x); v[1] = bf2f(iv.y); v[2] = bf2f(iv.z); v[3] = bf2f(iv.w);
  } else {
    const float4 iv = *(const float4*)((const float*)init + (size_t)m * NDIM + k);
    v[0] = iv.x; v[1] = iv.y; v[2] = iv.z; v[3] = iv.w;
  }
  float4 o0; o0.x = v[0]; o0.y = v[1]; o0.z = v[2]; o0.w = v[3];
  *(float4*)(out + OUT_VINIT + (size_t)m * NDIM + k) = o0;
  for (int t = 0; t < TSTEPS; ++t) {
    const int tp = tpos[t * BATCH + m];
    if ((tp >> 2) == tid) v[tp & 3] = 1.f - v[tp & 3];
  }
  float4 o; o.x = v[0]; o.y = v[1]; o.z = v[2]; o.w = v[3];
  *(float4*)(out + OUT_FINAL + (size_t)m * NDIM + k) = o;
  if (tid < 32) out[OUT_DELTA + m * 32 + tid] = (float)tpos[m * 32 + tid];
  if (tid < 64) {
    const int t = tid & 31;
    float s = tgt[t * BATCH + m] - logf(rowsum[t * BATCH + m]);
    s += __shfl_xor(s, 1, 32);
    s += __shfl_xor(s, 2, 32);
    s += __shfl_xor(s, 4, 32);
    s += __shfl_xor(s, 8, 32);
    s += __shfl_xor(s, 16, 32);
    if (tid == 0) out[OUT_TOTAL + m] = s;
  }
}

// ======================= FALLBACK PATH (R8, verified green) ==================
template <int ASRC, int EPI>
__global__ __launch_bounds__(256) void gemm_t(const void* __restrict__ A,
                                              const void* __restrict__ W,
                                              const float* __restrict__ bias,
                                              ushort* __restrict__ Cout,
                                              const int* __restrict__ tpos,
                                              float* __restrict__ rowsum,
                                              float* __restrict__ tgt,
                                              const uint32_t* __restrict__ flag,
                                              int tstep) {
  constexpr int BM = 64, BN = 64, BK = 32, BKP = 40, K = 1024;
  __shared__ ushort Asm[BM * BKP];
  __shared__ ushort Bsm[BN * BKP];
  const int tid = threadIdx.x;
  const int w = tid >> 6, lane = tid & 63;
  const int q = lane >> 4, r = lane & 15;
  const int n0 = blockIdx.x * BN;
  const int m0 = blockIdx.y * BM;
  const bool isbf = (*flag != 0);
  const int srow = tid >> 2, scol = (tid & 3) * 8;
  const int kk = tid >> 3, ng = (tid & 7) * 8;

  f32x4 acc[4];
  #pragma unroll
  for (int nt = 0; nt < 4; ++nt)
    #pragma unroll
    for (int e = 0; e < 4; ++e) acc[nt][e] = 0.f;

  for (int k0 = 0; k0 < K; k0 += BK) {
    u16x8 av;
    if constexpr (ASRC == 0) {
      if (isbf) {
        av = *(const u16x8*)((const ushort*)A + (size_t)(m0 + srow) * K + k0 + scol);
      } else {
        const float* fp = (const float*)A + (size_t)(m0 + srow) * K + k0 + scol;
        const float4 fa = *(const float4*)fp, fb = *(const float4*)(fp + 4);
        av[0] = f2bf(fa.x); av[1] = f2bf(fa.y); av[2] = f2bf(fa.z); av[3] = f2bf(fa.w);
        av[4] = f2bf(fb.x); av[5] = f2bf(fb.y); av[6] = f2bf(fb.z); av[7] = f2bf(fb.w);
      }
    } else {
      av = *(const u16x8*)((const ushort*)A + (size_t)(m0 + srow) * K + k0 + scol);
      if constexpr (ASRC == 1) {
        #pragma unroll
        for (int e = 0; e < 8; ++e) av[e] = (av[e] & 0x8000u) ? (unsigned short)0 : av[e];
      }
    }
    ushort bw[8];
    if (isbf) {
      const u16x8 wv = *(const u16x8*)((const ushort*)W + (size_t)(k0 + kk) * NDIM + n0 + ng);
      #pragma unroll
      for (int j = 0; j < 8; ++j) bw[j] = wv[j];
    } else {
      const float* fp = (const float*)W + (size_t)(k0 + kk) * NDIM + n0 + ng;
      const float4 fa = *(const float4*)fp, fb = *(const float4*)(fp + 4);
      bw[0] = f2bf(fa.x); bw[1] = f2bf(fa.y); bw[2] = f2bf(fa.z); bw[3] = f2bf(fa.w);
      bw[4] = f2bf(fb.x); bw[5] = f2bf(fb.y); bw[6] = f2bf(fb.z); bw[7] = f2bf(fb.w);
    }
    __syncthreads();
    *(u16x8*)(Asm + srow * BKP + scol) = av;
    #pragma unroll
    for (int j = 0; j < 8; ++j) Bsm[(ng + j) * BKP + kk] = bw[j];
    __syncthreads();
    const bf16x8 af = *(const bf16x8*)(Asm + (w * 16 + r) * BKP + q * 8);
    #pragma unroll
    for (int nt = 0; nt < 4; ++nt) {
      const bf16x8 bfr = *(const bf16x8*)(Bsm + (nt * 16 + r) * BKP + q * 8);
      acc[nt] = __builtin_amdgcn_mfma_f32_16x16x32_bf16(af, bfr, acc[nt], 0, 0, 0);
    }
  }

  if constexpr (EPI == 2) {
    #pragma unroll
    for (int reg = 0; reg < 4; ++reg) {
      const int grow = m0 + w * 16 + q * 4 + reg;
      const int tp = tpos[tstep * BATCH + grow];
      float s = 0.f;
      #pragma unroll
      for (int nt = 0; nt < 4; ++nt) {
        const int gcol = n0 + nt * 16 + r;
        const float v = acc[nt][reg] + bias[gcol];
        if (gcol == tp) tgt[grow] = v;
        s += __expf(v);
      }
      s += __shfl_xor(s, 1);
      s += __shfl_xor(s, 2);
      s += __shfl_xor(s, 4);
      s += __shfl_xor(s, 8);
      if (r == 0) atomicAdd(&rowsum[grow], s);
    }
  } else {
    #pragma unroll
    for (int nt = 0; nt < 4; ++nt) {
      #pragma unroll
      for (int reg = 0; reg < 4; ++reg) {
        const int grow = m0 + w * 16 + q * 4 + reg;
        const int gcol = n0 + nt * 16 + r;
        float v = acc[nt][reg] + bias[gcol];
        if constexpr (EPI == 1) v = (v > 0.f) ? v : 0.f;
        Cout[(size_t)grow * NDIM + gcol] = f2bf(v);
      }
    }
  }
}

__global__ __launch_bounds__(256) void step_k(ushort* __restrict__ a1,
                                              const void* __restrict__ init,
                                              const void* __restrict__ W1,
                                              const int* __restrict__ tpos,
                                              float* __restrict__ rowsum,
                                              const float* __restrict__ tgt,
                                              float* __restrict__ total,
                                              const uint32_t* __restrict__ flag,
                                              int t) {
  const int m = blockIdx.x;
  const int k = threadIdx.x * 4;
  const bool isbf = (*flag != 0);
  const int tp = tpos[t * BATCH + m];
  const float b0 = isbf ? bf2f(((const ushort*)init)[(size_t)m * NDIM + tp])
                        : ((const float*)init)[(size_t)m * NDIM + tp];
  int cnt = 0;
  for (int u = 0; u < t; ++u) cnt += (tpos[u * BATCH + m] == tp) ? 1 : 0;
  const float bit = (cnt & 1) ? (1.f - b0) : b0;
  const float s = 1.f - 2.f * bit;
  float wx, wy, wz, ww;
  if (isbf) {
    const ushort4 wv = *(const ushort4*)((const ushort*)W1 + (size_t)tp * HID + k);
    wx = bf2f(wv.x); wy = bf2f(wv.y); wz = bf2f(wv.z); ww = bf2f(wv.w);
  } else {
    const float4 wv = *(const float4*)((const float*)W1 + (size_t)tp * HID + k);
    wx = wv.x; wy = wv.y; wz = wv.z; ww = wv.w;
  }
  ushort4 a = *(const ushort4*)(a1 + (size_t)m * HID + k);
  a.x = f2bf(bf2f(a.x) + s * wx);
  a.y = f2bf(bf2f(a.y) + s * wy);
  a.z = f2bf(bf2f(a.z) + s * wz);
  a.w = f2bf(bf2f(a.w) + s * ww);
  *(ushort4*)(a1 + (size_t)m * HID + k) = a;
  if (threadIdx.x == 0) {
    total[m] += tgt[m] - logf(rowsum[m]);
    rowsum[m] = 0.f;
  }
}

__global__ __launch_bounds__(256) void finalize_k(const float* __restrict__ total,
                                                  float* __restrict__ out_total) {
  const int m = blockIdx.x * 256 + threadIdx.x;
  out_total[m] = total[m];
}

__global__ __launch_bounds__(256) void out_final_k(const void* __restrict__ init,
                                                   const int* __restrict__ tpos,
                                                   float* __restrict__ out,
                                                   const uint32_t* __restrict__ flag) {
  const int m = blockIdx.x;
  const int k = threadIdx.x * 4;
  const bool isbf = (*flag != 0);
  float v[4];
  if (isbf) {
    const ushort4 iv = *(const ushort4*)((const ushort*)init + (size_t)m * NDIM + k);
    v[0] = bf2f(iv.x); v[1] = bf2f(iv.y); v[2] = bf2f(iv.z); v[3] = bf2f(iv.w);
  } else {
    const float4 iv = *(const float4*)((const float*)init + (size_t)m * NDIM + k);
    v[0] = iv.x; v[1] = iv.y; v[2] = iv.z; v[3] = iv.w;
  }
  for (int t = 0; t < TSTEPS; ++t) {
    const int tp = tpos[t * BATCH + m];
    if ((tp >> 2) == (int)threadIdx.x) v[tp & 3] = 1.f - v[tp & 3];
  }
  float4 o; o.x = v[0]; o.y = v[1]; o.z = v[2]; o.w = v[3];
  *(float4*)(out + OUT_FINAL + (size_t)m * NDIM + k) = o;
}

__global__ __launch_bounds__(256) void out_vinit_k(const void* __restrict__ init,
                                                   float* __restrict__ out,
                                                   const uint32_t* __restrict__ flag) {
  const int i = (blockIdx.x * 256 + threadIdx.x) * 4;
  float4 o;
  if (*flag) {
    const ushort4 iv = *(const ushort4*)((const ushort*)init + i);
    o.x = bf2f(iv.x); o.y = bf2f(iv.y); o.z = bf2f(iv.z); o.w = bf2f(iv.w);
  } else {
    o = *(const float4*)((const float*)init + i);
  }
  *(float4*)(out + OUT_VINIT + i) = o;
}

__global__ __launch_bounds__(256) void out_delta_k(const int* __restrict__ tpos,
                                                   float* __restrict__ out) {
  const int i = blockIdx.x * 256 + threadIdx.x;
  out[OUT_DELTA + i] = (float)tpos[i];
}

extern "C" void kernel_launch(void* const* d_in, const int* in_sizes, int n_in,
                              void* d_out, int out_size, void* d_ws, size_t ws_size,
                              hipStream_t stream) {
  const void* init = d_in[0];
  const int* tpos  = (const int*)d_in[1];
  const void* W1 = d_in[2];
  const void* b1 = d_in[3];
  const void* W2 = d_in[4];
  const void* b2 = d_in[5];
  const void* W3 = d_in[6];
  const void* b3 = d_in[7];
  float* out = (float*)d_out;
  char* ws = (char*)d_ws;

  const size_t MB = 1024ull * 1024ull;
  int CH = TSTEPS;
  while (CH > 1 && (size_t)WF_H1 + (size_t)CH * 8 * MB > ws_size) CH >>= 1;
  const bool fast = (ws_size >= (size_t)WF_H1 + 8 * MB);

  if (fast) {
    ushort*   WT1    = (ushort*)(ws + WF_WT1);
    ushort*   WT2    = (ushort*)(ws + WF_WT2);
    ushort*   WT3    = (ushort*)(ws + WF_WT3);
    float*    a1f    = (float*)(ws + WF_A1);
    float*    biases = (float*)(ws + WF_BIAS);
    uint8_t*  signs  = (uint8_t*)(ws + WF_SIGNS);
    float*    rowsum = (float*)(ws + WF_ROWSUM);
    float*    tgt    = (float*)(ws + WF_TGT);
    uint32_t* flag   = (uint32_t*)(ws + WF_FLAG);
    ushort*   h1     = (ushort*)(ws + WF_H1);
    ushort*   h2     = (ushort*)(ws + WF_H1 + (size_t)CH * 4 * MB);

    flag_k<<<1, 256, 0, stream>>>(init, flag);
    canon_b_k<<<3, 256, 0, stream>>>(b1, b2, b3, biases, flag);
    canon_w3_k<<<dim3(32, 32, 3), dim3(32, 8), 0, stream>>>(W1, W2, W3, WT1, flag);
    sign_k<<<BATCH, 256, 0, stream>>>(init, tpos, signs, rowsum, tgt, flag);

    // a1 = init @ W1 + b1  (fp32 out)
    gemm_bt<1, 0><<<dim3(8, 16), 256, 0, stream>>>(init, WT1, biases + 0, a1f,
                                                   nullptr, nullptr, nullptr, flag, 0);

    for (int t0 = 0; t0 < TSTEPS; t0 += CH) {
      build_h1<<<BATCH, 256, 0, stream>>>(a1f, W1, signs, tpos, h1, flag, t0, CH);
      gemm_bt<0, 1><<<dim3(8, CH * 16), 256, 0, stream>>>(h1, WT2, biases + 1024, h2,
                                                          nullptr, nullptr, nullptr, flag, 0);
      gemm_bt<0, 2><<<dim3(8, CH * 16), 256, 0, stream>>>(h2, WT3, biases + 2048, nullptr,
                                                          tpos, rowsum, tgt, flag, t0 * BATCH);
    }
    outputs_k<<<BATCH, 256, 0, stream>>>(init, tpos, tgt, rowsum, out, flag);
  } else {
    // -------- fallback: R8 verified d_out-resident path --------
    ushort*   a1     = (ushort*)(out + OUT_FINAL);
    ushort*   h2     = (ushort*)(out + OUT_VINIT);
    char*     sc     = (char*)(out + OUT_DELTA);
    float*    rowsum = (float*)(sc + SC_ROWSUM);
    float*    tgt    = (float*)(sc + SC_TGT);
    float*    total  = (float*)(sc + SC_TOTAL);
    float*    biases = (float*)(sc + SC_BIAS);
    uint32_t* flag   = (uint32_t*)(sc + SC_FLAG);

    flag_k<<<1, 256, 0, stream>>>(init, flag);
    zero_k<<<24, 256, 0, stream>>>(rowsum);
    canon_b_k<<<3, 256, 0, stream>>>(b1, b2, b3, biases, flag);
    gemm_t<0, 0><<<dim3(16, 32), 256, 0, stream>>>(init, W1, biases + 0, a1,
                                                   nullptr, nullptr, nullptr, flag, 0);
    for (int t = 0; t < TSTEPS; ++t) {
      gemm_t<1, 1><<<dim3(16, 32), 256, 0, stream>>>(a1, W2, biases + 1024, h2,
                                                     nullptr, nullptr, nullptr, flag, 0);
      gemm_t<2, 2><<<dim3(16, 32), 256, 0, stream>>>(h2, W3, biases + 2048, nullptr,
                                                     tpos, rowsum, tgt, flag, t);
      step_k<<<BATCH, 256, 0, stream>>>(a1, init, W1, tpos, rowsum, tgt, total, flag, t);
    }
    finalize_k<<<8, 256, 0, stream>>>(total, out + OUT_TOTAL);
    out_final_k<<<BATCH, 256, 0, stream>>>(init, tpos, out, flag);
    out_vinit_k<<<2048, 256, 0, stream>>>(init, out, flag);
    out_delta_k<<<256, 256, 0, stream>>>(tpos, out);
  }
}

// Round 13
// 573.508 us; speedup vs baseline: 4.6698x; 1.0323x over previous
//
#include <hip/hip_runtime.h>
#include <stdint.h>

#define BATCH 2048
#define NDIM  1024
#define HID   1024
#define TSTEPS 32

// out layout (FP32 elems): final[2048*1024] | delta[32*2048] | total[2048] | vinit[2048*1024]
#define OUT_FINAL 0
#define OUT_DELTA 2097152
#define OUT_TOTAL 2162688
#define OUT_VINIT 2164736

// ---- fallback-path scratch inside the delta region (bytes from out+OUT_DELTA)
#define SC_ROWSUM 0
#define SC_TGT    8192
#define SC_TOTAL  16384
#define SC_BIAS   24576
#define SC_FLAG   36864

// ---- fast-path d_ws layout (bytes) ----
#define WF_WT1    0u           // 2 MB  W1^T bf16 [n][k]
#define WF_WT2    2097152u     // 2 MB
#define WF_WT3    4194304u     // 2 MB
#define WF_A1     6291456u     // 8 MB  fp32 a1 carry
#define WF_BIAS   14680064u    // 12 KB
#define WF_SIGNS  14692352u    // 64 KB
#define WF_ROWSUM 14757888u    // 256 KB
#define WF_TGT    15020032u    // 256 KB
#define WF_FLAG   15282176u    // 4 B
#define WF_H1     15286272u    // CH*4 MB bf16; h2 follows (CH*4 MB)

__device__ __forceinline__ float bf2f(ushort u) {
  union { uint32_t u; float f; } v; v.u = ((uint32_t)u) << 16; return v.f;
}
__device__ __forceinline__ ushort f2bf(float f) {
  union { float f; uint32_t u; } v; v.f = f;
  uint32_t u = v.u;
  u += 0x7fffu + ((u >> 16) & 1u);   // RNE
  return (ushort)(u >> 16);
}

typedef __attribute__((ext_vector_type(8))) short bf16x8;
typedef __attribute__((ext_vector_type(8))) unsigned short u16x8;
typedef __attribute__((ext_vector_type(4))) float f32x4;

__device__ __forceinline__ void gload_lds16(const void* g, void* l) {
  __builtin_amdgcn_global_load_lds((const __attribute__((address_space(1))) void*)g,
                                   (__attribute__((address_space(3))) void*)l, 16, 0, 0);
}

// ---- dtype flag ------------------------------------------------------------
__global__ __launch_bounds__(256) void flag_k(const void* __restrict__ init,
                                              uint32_t* __restrict__ flag) {
  const ushort* p = (const ushort*)init;
  __shared__ uint32_t acc[256];
  uint32_t a = 0;
  for (int i = threadIdx.x; i < 32768; i += 256) a |= p[2 * i];
  acc[threadIdx.x] = a;
  __syncthreads();
  for (int s = 128; s > 0; s >>= 1) {
    if (threadIdx.x < s) acc[threadIdx.x] |= acc[threadIdx.x + s];
    __syncthreads();
  }
  if (threadIdx.x == 0) *flag = (acc[0] != 0) ? 1u : 0u;
}

__global__ __launch_bounds__(256) void zero_k(float* __restrict__ p) {
  p[blockIdx.x * 256 + threadIdx.x] = 0.f;
}

// ---- canonicalize biases -> fp32 -------------------------------------------
__global__ __launch_bounds__(256) void canon_b_k(const void* b1, const void* b2,
                                                 const void* b3,
                                                 float* __restrict__ dst,
                                                 const uint32_t* __restrict__ flag) {
  const void* src = (blockIdx.x == 0) ? b1 : (blockIdx.x == 1) ? b2 : b3;
  float* d = dst + blockIdx.x * 1024;
  const bool isbf = (*flag != 0);
  for (int i = threadIdx.x; i < 1024; i += 256)
    d[i] = isbf ? bf2f(((const ushort*)src)[i]) : ((const float*)src)[i];
}

// ---- canonicalize + transpose all 3 weights --------------------------------
__global__ __launch_bounds__(256) void canon_w3_k(const void* __restrict__ S1,
                                                  const void* __restrict__ S2,
                                                  const void* __restrict__ S3,
                                                  ushort* __restrict__ D,
                                                  const uint32_t* __restrict__ flag) {
  __shared__ ushort tile[32][33];
  const void* S = (blockIdx.z == 0) ? S1 : (blockIdx.z == 1) ? S2 : S3;
  ushort* Dz = D + (size_t)blockIdx.z * 1024 * 1024;
  const int bx = blockIdx.x * 32, by = blockIdx.y * 32;
  const int tx = threadIdx.x, ty = threadIdx.y;  // (32,8)
  const bool isbf = (*flag != 0);
  #pragma unroll
  for (int i = 0; i < 32; i += 8) {
    const size_t idx = (size_t)(by + ty + i) * 1024 + bx + tx;
    tile[ty + i][tx] = isbf ? ((const ushort*)S)[idx] : f2bf(((const float*)S)[idx]);
  }
  __syncthreads();
  #pragma unroll
  for (int i = 0; i < 32; i += 8)
    Dz[(size_t)(bx + ty + i) * 1024 + by + tx] = tile[tx][ty + i];
}

// ---- bit trajectory + zero rowsum/tgt --------------------------------------
__global__ __launch_bounds__(256) void sign_k(const void* __restrict__ init,
                                              const int* __restrict__ tpos,
                                              uint8_t* __restrict__ signs,
                                              float* __restrict__ rowsum,
                                              float* __restrict__ tgt,
                                              const uint32_t* __restrict__ flag) {
  const int m = blockIdx.x, tid = threadIdx.x;
  const bool isbf = (*flag != 0);
  __shared__ float bits[NDIM];
  #pragma unroll
  for (int i = 0; i < 4; ++i) {
    const int k = tid + i * 256;
    bits[k] = isbf ? bf2f(((const ushort*)init)[(size_t)m * NDIM + k])
                   : ((const float*)init)[(size_t)m * NDIM + k];
  }
  __syncthreads();
  if (tid == 0) {
    for (int t = 0; t < TSTEPS; ++t) {
      const int tp = tpos[t * BATCH + m];
      const float b = bits[tp];
      signs[t * BATCH + m] = (uint8_t)(b != 0.f);
      bits[tp] = 1.f - b;
    }
  }
  if (tid < 32) rowsum[m * 32 + tid] = 0.f;
  else if (tid < 64) tgt[m * 32 + (tid - 32)] = 0.f;
}

// ====== FAST PATH: 128x128 GEMM, 512 threads (8 waves), high occupancy ======
// Each wave owns a 64x32 sub-tile: 4x2 MFMA, acc = 32 AGPR (half of the 256-
// thread variant) -> ~2 blocks/CU co-resident (~16 waves/CU) to cover the
// vmcnt drain at each barrier with the other block's MFMA work.
// Staging: one global_load_lds dwordx4 per matrix per iter (512 x 16 B = 8 KB).
// XCD swizzle: requires gridDim.y % 8 == 0.
template <int ASTAGE, int EPI>
__global__ __launch_bounds__(512) void gemm_bt(const void* __restrict__ A,
                                               const ushort* __restrict__ Bt,
                                               const float* __restrict__ bias,
                                               void* __restrict__ Cout,
                                               const int* __restrict__ tpos,
                                               float* __restrict__ rowsum,
                                               float* __restrict__ tgt,
                                               const uint32_t* __restrict__ flag,
                                               int rowbase) {
  constexpr int BM = 128, BN = 128, BK = 32, K = 1024;
  __shared__ ushort Asm[BM * BK];   // 8 KB
  __shared__ ushort Bsm[BN * BK];   // 8 KB
  const int tid = threadIdx.x;
  const int w = tid >> 6, lane = tid & 63;
  const int q = lane >> 4, r = lane & 15;

  // ---- XCD-aware (mb, nb) swizzle ----
  const int lid = blockIdx.y * gridDim.x + blockIdx.x;
  const int xcd = lid & 7;
  const int sl  = lid >> 3;
  const int mb  = xcd + 8 * (sl >> 3);
  const int nb  = sl & 7;
  const int n0 = nb * BN;
  const int m0 = mb * BM;
  const int wm = (w & 1) * 64;       // 2 wave-rows of 64
  const int wn = (w >> 1) * 32;      // 4 wave-cols of 32

  f32x4 acc[4][2];
  #pragma unroll
  for (int i = 0; i < 4; ++i)
    #pragma unroll
    for (int j = 0; j < 2; ++j)
      #pragma unroll
      for (int e = 0; e < 4; ++e) acc[i][j][e] = 0.f;

  // staging: thread covers row tid>>2, chunk (tid&3)*8 — exactly one 16B/matrix
  const int row = tid >> 2, c8 = (tid & 3) * 8;
  const bool isbf = (ASTAGE == 1) ? (*flag != 0) : true;

  for (int k0 = 0; k0 < K; k0 += BK) {
    if constexpr (ASTAGE == 0) {
      gload_lds16((const char*)A + ((size_t)(m0 + row) * K + k0 + c8) * 2,
                  (char*)Asm + tid * 16);
    } else {
      u16x8 av;
      if (isbf) {
        av = *(const u16x8*)((const ushort*)A + (size_t)(m0 + row) * K + k0 + c8);
      } else {
        const float* fp = (const float*)A + (size_t)(m0 + row) * K + k0 + c8;
        const float4 fa = *(const float4*)fp, fb = *(const float4*)(fp + 4);
        av[0] = f2bf(fa.x); av[1] = f2bf(fa.y); av[2] = f2bf(fa.z); av[3] = f2bf(fa.w);
        av[4] = f2bf(fb.x); av[5] = f2bf(fb.y); av[6] = f2bf(fb.z); av[7] = f2bf(fb.w);
      }
      *(u16x8*)((char*)Asm + tid * 16) = av;
    }
    gload_lds16((const char*)Bt + ((size_t)(n0 + row) * K + k0 + c8) * 2,
                (char*)Bsm + tid * 16);
    __syncthreads();
    bf16x8 af[4], bfr[2];
    #pragma unroll
    for (int t = 0; t < 4; ++t)
      af[t] = *(const bf16x8*)(Asm + (wm + t * 16 + r) * BK + q * 8);
    #pragma unroll
    for (int t = 0; t < 2; ++t)
      bfr[t] = *(const bf16x8*)(Bsm + (wn + t * 16 + r) * BK + q * 8);
    #pragma unroll
    for (int mt = 0; mt < 4; ++mt)
      #pragma unroll
      for (int nt = 0; nt < 2; ++nt)
        acc[mt][nt] = __builtin_amdgcn_mfma_f32_16x16x32_bf16(af[mt], bfr[nt], acc[mt][nt], 0, 0, 0);
    __syncthreads();
  }

  #pragma unroll
  for (int mt = 0; mt < 4; ++mt) {
    #pragma unroll
    for (int reg = 0; reg < 4; ++reg) {
      const int grow = m0 + wm + mt * 16 + q * 4 + reg;
      if constexpr (EPI == 2) {
        const int growg = rowbase + grow;
        const int tp = tpos[growg];
        float s2 = 0.f;
        #pragma unroll
        for (int nt = 0; nt < 2; ++nt) {
          const int gcol = n0 + wn + nt * 16 + r;
          const float v = acc[mt][nt][reg] + bias[gcol];
          if (gcol == tp) tgt[growg] = v;
          s2 += __expf(v);
        }
        s2 += __shfl_xor(s2, 1);
        s2 += __shfl_xor(s2, 2);
        s2 += __shfl_xor(s2, 4);
        s2 += __shfl_xor(s2, 8);
        if (r == 0) atomicAdd(&rowsum[growg], s2);
      } else {
        #pragma unroll
        for (int nt = 0; nt < 2; ++nt) {
          const int gcol = n0 + wn + nt * 16 + r;
          const float v = acc[mt][nt][reg] + bias[gcol];
          if constexpr (EPI == 0) {
            ((float*)Cout)[(size_t)grow * NDIM + gcol] = v;
          } else {
            ((ushort*)Cout)[(size_t)grow * NDIM + gcol] = f2bf(v > 0.f ? v : 0.f);
          }
        }
      }
    }
  }
}

// ---- h1 chunk: fp32 a1 recurrence + relu -> bf16 ---------------------------
__global__ __launch_bounds__(256) void build_h1(float* __restrict__ a1,
                                                const void* __restrict__ W1,
                                                const uint8_t* __restrict__ signs,
                                                const int* __restrict__ tpos,
                                                ushort* __restrict__ h1,
                                                const uint32_t* __restrict__ flag,
                                                int t0, int nsteps) {
  const int m = blockIdx.x;
  const int k = threadIdx.x * 4;
  const bool isbf = (*flag != 0);
  float4 a = *(const float4*)(a1 + (size_t)m * HID + k);
  for (int t = 0; t < nsteps; ++t) {
    ushort4 h;
    h.x = f2bf(a.x > 0.f ? a.x : 0.f);
    h.y = f2bf(a.y > 0.f ? a.y : 0.f);
    h.z = f2bf(a.z > 0.f ? a.z : 0.f);
    h.w = f2bf(a.w > 0.f ? a.w : 0.f);
    *(ushort4*)(h1 + ((size_t)(t * BATCH + m)) * HID + k) = h;
    const int tg = t0 + t;
    const int tp = tpos[tg * BATCH + m];
    const float s = 1.f - 2.f * (float)signs[tg * BATCH + m];
    float wx, wy, wz, ww;
    if (isbf) {
      const ushort4 wv = *(const ushort4*)((const ushort*)W1 + (size_t)tp * HID + k);
      wx = bf2f(wv.x); wy = bf2f(wv.y); wz = bf2f(wv.z); ww = bf2f(wv.w);
    } else {
      const float4 wv = *(const float4*)((const float*)W1 + (size_t)tp * HID + k);
      wx = wv.x; wy = wv.y; wz = wv.z; ww = wv.w;
    }
    a.x += s * wx; a.y += s * wy; a.z += s * wz; a.w += s * ww;
  }
  *(float4*)(a1 + (size_t)m * HID + k) = a;
}

// ---- merged outputs: final+vinit (row m), delta, total_log -----------------
__global__ __launch_bounds__(256) void outputs_k(const void* __restrict__ init,
                                                 const int* __restrict__ tpos,
                                                 const float* __restrict__ tgt,
                                                 const float* __restrict__ rowsum,
                                                 float* __restrict__ out,
                                                 const uint32_t* __restrict__ flag) {
  const int m = blockIdx.x;
  const int tid = threadIdx.x;
  const int k = tid * 4;
  const bool isbf = (*flag != 0);
  float v[4];
  if (isbf) {
    const ushort4 iv = *(const ushort4*)((const ushort*)init + (size_t)m * NDIM + k);
    v[0] = bf2f(iv.x); v[1] = bf2f(iv.y); v[2] = bf2f(iv.z); v[3] = bf2f(iv.w);
  } else {
    const float4 iv = *(const float4*)((const float*)init + (size_t)m * NDIM + k);
    v[0] = iv.x; v[1] = iv.y; v[2] = iv.z; v[3] = iv.w;
  }
  float4 o0; o0.x = v[0]; o0.y = v[1]; o0.z = v[2]; o0.w = v[3];
  *(float4*)(out + OUT_VINIT + (size_t)m * NDIM + k) = o0;
  for (int t = 0; t < TSTEPS; ++t) {
    const int tp = tpos[t * BATCH + m];
    if ((tp >> 2) == tid) v[tp & 3] = 1.f - v[tp & 3];
  }
  float4 o; o.x = v[0]; o.y = v[1]; o.z = v[2]; o.w = v[3];
  *(float4*)(out + OUT_FINAL + (size_t)m * NDIM + k) = o;
  if (tid < 32) out[OUT_DELTA + m * 32 + tid] = (float)tpos[m * 32 + tid];
  if (tid < 64) {
    const int t = tid & 31;
    float s = tgt[t * BATCH + m] - logf(rowsum[t * BATCH + m]);
    s += __shfl_xor(s, 1, 32);
    s += __shfl_xor(s, 2, 32);
    s += __shfl_xor(s, 4, 32);
    s += __shfl_xor(s, 8, 32);
    s += __shfl_xor(s, 16, 32);
    if (tid == 0) out[OUT_TOTAL + m] = s;
  }
}

// ======================= FALLBACK PATH (R8, verified green) ==================
template <int ASRC, int EPI>
__global__ __launch_bounds__(256) void gemm_t(const void* __restrict__ A,
                                              const void* __restrict__ W,
                                              const float* __restrict__ bias,
                                              ushort* __restrict__ Cout,
                                              const int* __restrict__ tpos,
                                              float* __restrict__ rowsum,
                                              float* __restrict__ tgt,
                                              const uint32_t* __restrict__ flag,
                                              int tstep) {
  constexpr int BM = 64, BN = 64, BK = 32, BKP = 40, K = 1024;
  __shared__ ushort Asm[BM * BKP];
  __shared__ ushort Bsm[BN * BKP];
  const int tid = threadIdx.x;
  const int w = tid >> 6, lane = tid & 63;
  const int q = lane >> 4, r = lane & 15;
  const int n0 = blockIdx.x * BN;
  const int m0 = blockIdx.y * BM;
  const bool isbf = (*flag != 0);
  const int srow = tid >> 2, scol = (tid & 3) * 8;
  const int kk = tid >> 3, ng = (tid & 7) * 8;

  f32x4 acc[4];
  #pragma unroll
  for (int nt = 0; nt < 4; ++nt)
    #pragma unroll
    for (int e = 0; e < 4; ++e) acc[nt][e] = 0.f;

  for (int k0 = 0; k0 < K; k0 += BK) {
    u16x8 av;
    if constexpr (ASRC == 0) {
      if (isbf) {
        av = *(const u16x8*)((const ushort*)A + (size_t)(m0 + srow) * K + k0 + scol);
      } else {
        const float* fp = (const float*)A + (size_t)(m0 + srow) * K + k0 + scol;
        const float4 fa = *(const float4*)fp, fb = *(const float4*)(fp + 4);
        av[0] = f2bf(fa.x); av[1] = f2bf(fa.y); av[2] = f2bf(fa.z); av[3] = f2bf(fa.w);
        av[4] = f2bf(fb.x); av[5] = f2bf(fb.y); av[6] = f2bf(fb.z); av[7] = f2bf(fb.w);
      }
    } else {
      av = *(const u16x8*)((const ushort*)A + (size_t)(m0 + srow) * K + k0 + scol);
      if constexpr (ASRC == 1) {
        #pragma unroll
        for (int e = 0; e < 8; ++e) av[e] = (av[e] & 0x8000u) ? (unsigned short)0 : av[e];
      }
    }
    ushort bw[8];
    if (isbf) {
      const u16x8 wv = *(const u16x8*)((const ushort*)W + (size_t)(k0 + kk) * NDIM + n0 + ng);
      #pragma unroll
      for (int j = 0; j < 8; ++j) bw[j] = wv[j];
    } else {
      const float* fp = (const float*)W + (size_t)(k0 + kk) * NDIM + n0 + ng;
      const float4 fa = *(const float4*)fp, fb = *(const float4*)(fp + 4);
      bw[0] = f2bf(fa.x); bw[1] = f2bf(fa.y); bw[2] = f2bf(fa.z); bw[3] = f2bf(fa.w);
      bw[4] = f2bf(fb.x); bw[5] = f2bf(fb.y); bw[6] = f2bf(fb.z); bw[7] = f2bf(fb.w);
    }
    __syncthreads();
    *(u16x8*)(Asm + srow * BKP + scol) = av;
    #pragma unroll
    for (int j = 0; j < 8; ++j) Bsm[(ng + j) * BKP + kk] = bw[j];
    __syncthreads();
    const bf16x8 af = *(const bf16x8*)(Asm + (w * 16 + r) * BKP + q * 8);
    #pragma unroll
    for (int nt = 0; nt < 4; ++nt) {
      const bf16x8 bfr = *(const bf16x8*)(Bsm + (nt * 16 + r) * BKP + q * 8);
      acc[nt] = __builtin_amdgcn_mfma_f32_16x16x32_bf16(af, bfr, acc[nt], 0, 0, 0);
    }
  }

  if constexpr (EPI == 2) {
    #pragma unroll
    for (int reg = 0; reg < 4; ++reg) {
      const int grow = m0 + w * 16 + q * 4 + reg;
      const int tp = tpos[tstep * BATCH + grow];
      float s = 0.f;
      #pragma unroll
      for (int nt = 0; nt < 4; ++nt) {
        const int gcol = n0 + nt * 16 + r;
        const float v = acc[nt][reg] + bias[gcol];
        if (gcol == tp) tgt[grow] = v;
        s += __expf(v);
      }
      s += __shfl_xor(s, 1);
      s += __shfl_xor(s, 2);
      s += __shfl_xor(s, 4);
      s += __shfl_xor(s, 8);
      if (r == 0) atomicAdd(&rowsum[grow], s);
    }
  } else {
    #pragma unroll
    for (int nt = 0; nt < 4; ++nt) {
      #pragma unroll
      for (int reg = 0; reg < 4; ++reg) {
        const int grow = m0 + w * 16 + q * 4 + reg;
        const int gcol = n0 + nt * 16 + r;
        float v = acc[nt][reg] + bias[gcol];
        if constexpr (EPI == 1) v = (v > 0.f) ? v : 0.f;
        Cout[(size_t)grow * NDIM + gcol] = f2bf(v);
      }
    }
  }
}

__global__ __launch_bounds__(256) void step_k(ushort* __restrict__ a1,
                                              const void* __restrict__ init,
                                              const void* __restrict__ W1,
                                              const int* __restrict__ tpos,
                                              float* __restrict__ rowsum,
                                              const float* __restrict__ tgt,
                                              float* __restrict__ total,
                                              const uint32_t* __restrict__ flag,
                                              int t) {
  const int m = blockIdx.x;
  const int k = threadIdx.x * 4;
  const bool isbf = (*flag != 0);
  const int tp = tpos[t * BATCH + m];
  const float b0 = isbf ? bf2f(((const ushort*)init)[(size_t)m * NDIM + tp])
                        : ((const float*)init)[(size_t)m * NDIM + tp];
  int cnt = 0;
  for (int u = 0; u < t; ++u) cnt += (tpos[u * BATCH + m] == tp) ? 1 : 0;
  const float bit = (cnt & 1) ? (1.f - b0) : b0;
  const float s = 1.f - 2.f * bit;
  float wx, wy, wz, ww;
  if (isbf) {
    const ushort4 wv = *(const ushort4*)((const ushort*)W1 + (size_t)tp * HID + k);
    wx = bf2f(wv.x); wy = bf2f(wv.y); wz = bf2f(wv.z); ww = bf2f(wv.w);
  } else {
    const float4 wv = *(const float4*)((const float*)W1 + (size_t)tp * HID + k);
    wx = wv.x; wy = wv.y; wz = wv.z; ww = wv.w;
  }
  ushort4 a = *(const ushort4*)(a1 + (size_t)m * HID + k);
  a.x = f2bf(bf2f(a.x) + s * wx);
  a.y = f2bf(bf2f(a.y) + s * wy);
  a.z = f2bf(bf2f(a.z) + s * wz);
  a.w = f2bf(bf2f(a.w) + s * ww);
  *(ushort4*)(a1 + (size_t)m * HID + k) = a;
  if (threadIdx.x == 0) {
    total[m] += tgt[m] - logf(rowsum[m]);
    rowsum[m] = 0.f;
  }
}

__global__ __launch_bounds__(256) void finalize_k(const float* __restrict__ total,
                                                  float* __restrict__ out_total) {
  const int m = blockIdx.x * 256 + threadIdx.x;
  out_total[m] = total[m];
}

__global__ __launch_bounds__(256) void out_final_k(const void* __restrict__ init,
                                                   const int* __restrict__ tpos,
                                                   float* __restrict__ out,
                                                   const uint32_t* __restrict__ flag) {
  const int m = blockIdx.x;
  const int k = threadIdx.x * 4;
  const bool isbf = (*flag != 0);
  float v[4];
  if (isbf) {
    const ushort4 iv = *(const ushort4*)((const ushort*)init + (size_t)m * NDIM + k);
    v[0] = bf2f(iv.x); v[1] = bf2f(iv.y); v[2] = bf2f(iv.z); v[3] = bf2f(iv.w);
  } else {
    const float4 iv = *(const float4*)((const float*)init + (size_t)m * NDIM + k);
    v[0] = iv.x; v[1] = iv.y; v[2] = iv.z; v[3] = iv.w;
  }
  for (int t = 0; t < TSTEPS; ++t) {
    const int tp = tpos[t * BATCH + m];
    if ((tp >> 2) == (int)threadIdx.x) v[tp & 3] = 1.f - v[tp & 3];
  }
  float4 o; o.x = v[0]; o.y = v[1]; o.z = v[2]; o.w = v[3];
  *(float4*)(out + OUT_FINAL + (size_t)m * NDIM + k) = o;
}

__global__ __launch_bounds__(256) void out_vinit_k(const void* __restrict__ init,
                                                   float* __restrict__ out,
                                                   const uint32_t* __restrict__ flag) {
  const int i = (blockIdx.x * 256 + threadIdx.x) * 4;
  float4 o;
  if (*flag) {
    const ushort4 iv = *(const ushort4*)((const ushort*)init + i);
    o.x = bf2f(iv.x); o.y = bf2f(iv.y); o.z = bf2f(iv.z); o.w = bf2f(iv.w);
  } else {
    o = *(const float4*)((const float*)init + i);
  }
  *(float4*)(out + OUT_VINIT + i) = o;
}

__global__ __launch_bounds__(256) void out_delta_k(const int* __restrict__ tpos,
                                                   float* __restrict__ out) {
  const int i = blockIdx.x * 256 + threadIdx.x;
  out[OUT_DELTA + i] = (float)tpos[i];
}

extern "C" void kernel_launch(void* const* d_in, const int* in_sizes, int n_in,
                              void* d_out, int out_size, void* d_ws, size_t ws_size,
                              hipStream_t stream) {
  const void* init = d_in[0];
  const int* tpos  = (const int*)d_in[1];
  const void* W1 = d_in[2];
  const void* b1 = d_in[3];
  const void* W2 = d_in[4];
  const void* b2 = d_in[5];
  const void* W3 = d_in[6];
  const void* b3 = d_in[7];
  float* out = (float*)d_out;
  char* ws = (char*)d_ws;

  const size_t MB = 1024ull * 1024ull;
  int CH = TSTEPS;
  while (CH > 1 && (size_t)WF_H1 + (size_t)CH * 8 * MB > ws_size) CH >>= 1;
  const bool fast = (ws_size >= (size_t)WF_H1 + 8 * MB);

  if (fast) {
    ushort*   WT1    = (ushort*)(ws + WF_WT1);
    ushort*   WT2    = (ushort*)(ws + WF_WT2);
    ushort*   WT3    = (ushort*)(ws + WF_WT3);
    float*    a1f    = (float*)(ws + WF_A1);
    float*    biases = (float*)(ws + WF_BIAS);
    uint8_t*  signs  = (uint8_t*)(ws + WF_SIGNS);
    float*    rowsum = (float*)(ws + WF_ROWSUM);
    float*    tgt    = (float*)(ws + WF_TGT);
    uint32_t* flag   = (uint32_t*)(ws + WF_FLAG);
    ushort*   h1     = (ushort*)(ws + WF_H1);
    ushort*   h2     = (ushort*)(ws + WF_H1 + (size_t)CH * 4 * MB);

    flag_k<<<1, 256, 0, stream>>>(init, flag);
    canon_b_k<<<3, 256, 0, stream>>>(b1, b2, b3, biases, flag);
    canon_w3_k<<<dim3(32, 32, 3), dim3(32, 8), 0, stream>>>(W1, W2, W3, WT1, flag);
    sign_k<<<BATCH, 256, 0, stream>>>(init, tpos, signs, rowsum, tgt, flag);

    // a1 = init @ W1 + b1  (fp32 out)
    gemm_bt<1, 0><<<dim3(8, 16), 512, 0, stream>>>(init, WT1, biases + 0, a1f,
                                                   nullptr, nullptr, nullptr, flag, 0);

    for (int t0 = 0; t0 < TSTEPS; t0 += CH) {
      build_h1<<<BATCH, 256, 0, stream>>>(a1f, W1, signs, tpos, h1, flag, t0, CH);
      gemm_bt<0, 1><<<dim3(8, CH * 16), 512, 0, stream>>>(h1, WT2, biases + 1024, h2,
                                                          nullptr, nullptr, nullptr, flag, 0);
      gemm_bt<0, 2><<<dim3(8, CH * 16), 512, 0, stream>>>(h2, WT3, biases + 2048, nullptr,
                                                          tpos, rowsum, tgt, flag, t0 * BATCH);
    }
    outputs_k<<<BATCH, 256, 0, stream>>>(init, tpos, tgt, rowsum, out, flag);
  } else {
    // -------- fallback: R8 verified d_out-resident path --------
    ushort*   a1     = (ushort*)(out + OUT_FINAL);
    ushort*   h2     = (ushort*)(out + OUT_VINIT);
    char*     sc     = (char*)(out + OUT_DELTA);
    float*    rowsum = (float*)(sc + SC_ROWSUM);
    float*    tgt    = (float*)(sc + SC_TGT);
    float*    total  = (float*)(sc + SC_TOTAL);
    float*    biases = (float*)(sc + SC_BIAS);
    uint32_t* flag   = (uint32_t*)(sc + SC_FLAG);

    flag_k<<<1, 256, 0, stream>>>(init, flag);
    zero_k<<<24, 256, 0, stream>>>(rowsum);
    canon_b_k<<<3, 256, 0, stream>>>(b1, b2, b3, biases, flag);
    gemm_t<0, 0><<<dim3(16, 32), 256, 0, stream>>>(init, W1, biases + 0, a1,
                                                   nullptr, nullptr, nullptr, flag, 0);
    for (int t = 0; t < TSTEPS; ++t) {
      gemm_t<1, 1><<<dim3(16, 32), 256, 0, stream>>>(a1, W2, biases + 1024, h2,
                                                     nullptr, nullptr, nullptr, flag, 0);
      gemm_t<2, 2><<<dim3(16, 32), 256, 0, stream>>>(h2, W3, biases + 2048, nullptr,
                                                     tpos, rowsum, tgt, flag, t);
      step_k<<<BATCH, 256, 0, stream>>>(a1, init, W1, tpos, rowsum, tgt, total, flag, t);
    }
    finalize_k<<<8, 256, 0, stream>>>(total, out + OUT_TOTAL);
    out_final_k<<<BATCH, 256, 0, stream>>>(init, tpos, out, flag);
    out_vinit_k<<<2048, 256, 0, stream>>>(init, out, flag);
    out_delta_k<<<256, 256, 0, stream>>>(tpos, out);
  }
}